// Round 6
// baseline (613.316 us; speedup 1.0000x reference)
//
#include <hip/hip_runtime.h>
#include <hip/hip_bf16.h>
#include <hip/hip_fp16.h>

#define NN 50000
#define NE 800000
#define EPS 1e-5f
#define NW 782            // ceil(NN/64) windows of 64 nodes
#define WFB 100           // wfill/whist blocks
#define CHUNK (NE / WFB)  // 8000 edges per wfill block

typedef _Float16 f16;
typedef _Float16 f16x8 __attribute__((ext_vector_type(8)));
typedef float f32x4 __attribute__((ext_vector_type(4)));

// ---------------- window partition build ----------------

__global__ void k_zero(int* __restrict__ p, int n) {
    int i = blockIdx.x * blockDim.x + threadIdx.x;
    for (; i < n; i += gridDim.x * blockDim.x) p[i] = 0;
}

// window histogram: LDS-merged then one global atomic per (block,window)
__global__ __launch_bounds__(256) void k_whist(const int* __restrict__ tgt,
                                               int* __restrict__ wh, int E4) {
    __shared__ int lh[NW];
    int tid = threadIdx.x;
    for (int i = tid; i < NW; i += 256) lh[i] = 0;
    __syncthreads();
    for (int i = blockIdx.x * 256 + tid; i < E4; i += gridDim.x * 256) {
        int4 t = ((const int4*)tgt)[i];
        atomicAdd(&lh[t.x >> 6], 1);
        atomicAdd(&lh[t.y >> 6], 1);
        atomicAdd(&lh[t.z >> 6], 1);
        atomicAdd(&lh[t.w >> 6], 1);
    }
    __syncthreads();
    for (int i = tid; i < NW; i += 256) {
        int c = lh[i];
        if (c) atomicAdd(&wh[i], c);
    }
}

// single-block carry scan over NW values -> wrow[0..NW], wcur copy
__global__ __launch_bounds__(256) void k_wscan(const int* __restrict__ wh,
                                               int* __restrict__ wrow,
                                               int* __restrict__ wcur, int n) {
    __shared__ int buf[256];
    __shared__ int carry_s;
    int tid = threadIdx.x;
    if (tid == 0) carry_s = 0;
    __syncthreads();
    for (int base = 0; base < n; base += 256) {
        int i = base + tid;
        int v = (i < n) ? wh[i] : 0;
        buf[tid] = v;
        __syncthreads();
        for (int off = 1; off < 256; off <<= 1) {
            int t = (tid >= off) ? buf[tid - off] : 0;
            __syncthreads();
            buf[tid] += t;
            __syncthreads();
        }
        int excl = buf[tid] - v;
        int c = carry_s;
        if (i < n) { wrow[i] = c + excl; wcur[i] = c + excl; }
        __syncthreads();
        if (tid == 0) carry_s = c + buf[255];
        __syncthreads();
    }
    if (tid == 0) wrow[n] = carry_s;
}

// partition edges into windows with per-block span reservation:
// pass A: LDS-hist chunk; pass B: reserve spans (1 atomic per window);
// pass C: write packed (src<<6|tgt&63) into own span (single-XCD lines).
__global__ __launch_bounds__(256) void k_wfill(const int* __restrict__ src,
                                               const int* __restrict__ tgt,
                                               int* __restrict__ wcur,
                                               int* __restrict__ col) {
    __shared__ int lh[NW];
    __shared__ int sb[NW];
    int tid = threadIdx.x;
    int e0 = blockIdx.x * CHUNK;
    int i4hi = (e0 + CHUNK) >> 2;
    for (int i = tid; i < NW; i += 256) lh[i] = 0;
    __syncthreads();
#pragma unroll
    for (int j = 0; j < 8; j++) {
        int i4 = (e0 >> 2) + j * 256 + tid;
        if (i4 < i4hi) {
            int4 t = ((const int4*)tgt)[i4];
            atomicAdd(&lh[t.x >> 6], 1);
            atomicAdd(&lh[t.y >> 6], 1);
            atomicAdd(&lh[t.z >> 6], 1);
            atomicAdd(&lh[t.w >> 6], 1);
        }
    }
    __syncthreads();
    for (int i = tid; i < NW; i += 256) {
        int c = lh[i];
        sb[i] = c ? atomicAdd(&wcur[i], c) : 0;
        lh[i] = 0;
    }
    __syncthreads();
#pragma unroll
    for (int j = 0; j < 8; j++) {
        int i4 = (e0 >> 2) + j * 256 + tid;
        if (i4 < i4hi) {
            int4 t = ((const int4*)tgt)[i4];
            int4 s = ((const int4*)src)[i4];
            int w0 = t.x >> 6, r0 = atomicAdd(&lh[w0], 1);
            col[sb[w0] + r0] = (s.x << 6) | (t.x & 63);
            int w1 = t.y >> 6, r1 = atomicAdd(&lh[w1], 1);
            col[sb[w1] + r1] = (s.y << 6) | (t.y & 63);
            int w2 = t.z >> 6, r2 = atomicAdd(&lh[w2], 1);
            col[sb[w2] + r2] = (s.z << 6) | (t.z & 63);
            int w3 = t.w >> 6, r3 = atomicAdd(&lh[w3], 1);
            col[sb[w3] + r3] = (s.w << 6) | (t.w & 63);
        }
    }
}

// ---------------- weight prep (once, tiny) ----------------
__global__ __launch_bounds__(256) void k_prep(const float* __restrict__ Win,
                                              const float* __restrict__ Wl,
                                              const float* __restrict__ Wr,
                                              f16* __restrict__ WinT,
                                              f16* __restrict__ W2T) {
    int i0 = blockIdx.x * 256 + threadIdx.x;
    for (int i = i0; i < 128 * 104; i += gridDim.x * 256) {
        int c = i / 104, k = i - c * 104;
        float v = (k < 84) ? Win[k * 128 + c] : 0.f;
        WinT[c * 104 + k] = (f16)v;
    }
    for (int i = i0; i < 128 * 136; i += gridDim.x * 256) {
        int c = i / 136, k = i - c * 136;
        float v = 0.f;
        if (k < 128) v = (c < 64) ? Wl[k * 64 + c] : Wr[k * 64 + (c - 64)];
        W2T[c * 136 + k] = (f16)v;
    }
}

// ---------------- MFMA fused input stage (unchanged from R5) ----------------
__global__ __launch_bounds__(256) void k_in_proj1(const float* __restrict__ x,
                                                  const f16* __restrict__ WinT,
                                                  const float* __restrict__ bin,
                                                  const f16* __restrict__ W2T,
                                                  const float* __restrict__ bl,
                                                  f16* __restrict__ p1h,
                                                  f16* __restrict__ r1h, int N) {
    __shared__ __align__(16) f16 xs[32 * 104];
    __shared__ __align__(16) f16 hs[32 * 136];
    int tid = threadIdx.x;
    int node0 = blockIdx.x * 32;
    int lane = tid & 63;
    int wv = tid >> 6;
    int r = lane & 15;
    int q = lane >> 4;

    f16x8 b1[2][3];
#pragma unroll
    for (int nt = 0; nt < 2; nt++) {
        int c = (2 * wv + nt) * 16 + r;
#pragma unroll
        for (int ks = 0; ks < 3; ks++)
            b1[nt][ks] = *(const f16x8*)&WinT[c * 104 + ks * 32 + q * 8];
    }
    for (int i = tid; i < 32 * 96; i += 256) {
        int nd = i / 96, k = i - nd * 96;
        int g = node0 + nd;
        float v = (g < N && k < 84) ? x[(size_t)g * 84 + k] : 0.f;
        xs[nd * 104 + k] = (f16)v;
    }
    __syncthreads();

    f32x4 acc[2][2] = {};
#pragma unroll
    for (int ks = 0; ks < 3; ks++) {
        int k0 = ks * 32;
        f16x8 a[2];
#pragma unroll
        for (int mt = 0; mt < 2; mt++)
            a[mt] = *(const f16x8*)&xs[(mt * 16 + r) * 104 + k0 + q * 8];
#pragma unroll
        for (int mt = 0; mt < 2; mt++)
#pragma unroll
            for (int nt = 0; nt < 2; nt++)
                acc[mt][nt] = __builtin_amdgcn_mfma_f32_16x16x32_f16(a[mt], b1[nt][ks], acc[mt][nt], 0, 0, 0);
    }

    f16x8 b2[2][4];
#pragma unroll
    for (int nt = 0; nt < 2; nt++) {
        int c = (2 * wv + nt) * 16 + r;
#pragma unroll
        for (int ks = 0; ks < 4; ks++)
            b2[nt][ks] = *(const f16x8*)&W2T[c * 136 + ks * 32 + q * 8];
    }

#pragma unroll
    for (int nt = 0; nt < 2; nt++) {
        int c = (2 * wv + nt) * 16 + r;
        float bb = bin[c];
#pragma unroll
        for (int mt = 0; mt < 2; mt++)
#pragma unroll
            for (int v = 0; v < 4; v++) {
                int row = mt * 16 + q * 4 + v;
                float val = acc[mt][nt][v] + bb;
                hs[row * 136 + c] = (f16)(val > 0.f ? val : 0.f);
            }
    }
    __syncthreads();

    f32x4 acc2[2][2] = {};
#pragma unroll
    for (int ks = 0; ks < 4; ks++) {
        int k0 = ks * 32;
        f16x8 a[2];
#pragma unroll
        for (int mt = 0; mt < 2; mt++)
            a[mt] = *(const f16x8*)&hs[(mt * 16 + r) * 136 + k0 + q * 8];
#pragma unroll
        for (int mt = 0; mt < 2; mt++)
#pragma unroll
            for (int nt = 0; nt < 2; nt++)
                acc2[mt][nt] = __builtin_amdgcn_mfma_f32_16x16x32_f16(a[mt], b2[nt][ks], acc2[mt][nt], 0, 0, 0);
    }

#pragma unroll
    for (int nt = 0; nt < 2; nt++) {
        int c = (2 * wv + nt) * 16 + r;
        float bb = (c >= 64) ? bl[c - 64] : 0.f;
#pragma unroll
        for (int mt = 0; mt < 2; mt++)
#pragma unroll
            for (int v = 0; v < 4; v++) {
                int n = node0 + mt * 16 + q * 4 + v;
                if (n < N) {
                    float val = acc2[mt][nt][v];
                    if (c < 64) p1h[(size_t)n * 64 + c] = (f16)val;
                    else        r1h[(size_t)n * 64 + (c - 64)] = (f16)(val + bb);
                }
            }
    }
}

// ---------------- windowed aggregation layer 1 (64 ch) ----------------
// block = 64-node window. Edge-parallel LDS f32 accumulate, then LN + proj2.
__global__ __launch_bounds__(256) void k_agg1w(const __half2* __restrict__ p1v,
                                               const __half2* __restrict__ r1v,
                                               const int* __restrict__ wrow,
                                               const int* __restrict__ col,
                                               const float* __restrict__ g1,
                                               const float* __restrict__ be1,
                                               const float* __restrict__ Wl2,
                                               const float* __restrict__ Wr2,
                                               const float* __restrict__ bl2,
                                               __half* __restrict__ p2h,
                                               __half* __restrict__ r2h, int N) {
    __shared__ float acc[64][65];     // padded: bank = (tl + ch) % 32
    __shared__ float Wlds[2 * 2048];  // Wl2 | Wr2
    __shared__ int cnt[64];
    int tid = threadIdx.x;
    for (int i = tid; i < 2048; i += 256) {
        Wlds[i] = Wl2[i];
        Wlds[2048 + i] = Wr2[i];
    }
    for (int i = tid; i < 64 * 65; i += 256) ((float*)acc)[i] = 0.f;
    if (tid < 64) cnt[tid] = 0;
    __syncthreads();

    int wb = blockIdx.x;
    int base = wb << 6;
    int s0 = wrow[wb], s1 = wrow[wb + 1];
    int lane = tid & 31;
    int g = tid >> 5;   // 8 groups of 32 lanes, one edge each

    int e = s0 + g;
    for (; e + 8 < s1; e += 16) {
        int pk0 = col[e];
        int pk1 = col[e + 8];
        int sA = pk0 >> 6, tA = pk0 & 63;
        int sB = pk1 >> 6, tB = pk1 & 63;
        float2 vA = __half22float2(p1v[(size_t)sA * 32 + lane]);
        float2 vB = __half22float2(p1v[(size_t)sB * 32 + lane]);
        atomicAdd(&acc[tA][2 * lane], vA.x);
        atomicAdd(&acc[tA][2 * lane + 1], vA.y);
        atomicAdd(&acc[tB][2 * lane], vB.x);
        atomicAdd(&acc[tB][2 * lane + 1], vB.y);
        if (lane == 0) { atomicAdd(&cnt[tA], 1); atomicAdd(&cnt[tB], 1); }
    }
    if (e < s1) {
        int pk0 = col[e];
        int sA = pk0 >> 6, tA = pk0 & 63;
        float2 vA = __half22float2(p1v[(size_t)sA * 32 + lane]);
        atomicAdd(&acc[tA][2 * lane], vA.x);
        atomicAdd(&acc[tA][2 * lane + 1], vA.y);
        if (lane == 0) atomicAdd(&cnt[tA], 1);
    }
    __syncthreads();

    // LN phase: 8 rounds x 8 groups; y overwrites acc rows
    int cc = tid & 31;
    int grp = tid >> 5;
#pragma unroll
    for (int rnd = 0; rnd < 8; rnd++) {
        int tl = rnd * 8 + grp;
        int n = base + tl;
        if (n < N) {
            int c = cnt[tl];
            float inv = 1.f / (float)(c > 1 ? c : 1);
            float2 rr = __half22float2(r1v[(size_t)n * 32 + cc]);
            float vx = acc[tl][2 * cc] * inv + rr.x;
            float vy = acc[tl][2 * cc + 1] * inv + rr.y;
            float s = vx + vy;
#pragma unroll
            for (int o = 1; o < 32; o <<= 1) s += __shfl_xor(s, o, 32);
            float m = s * (1.f / 64.f);
            float dx = vx - m, dy = vy - m;
            float qv = dx * dx + dy * dy;
#pragma unroll
            for (int o = 1; o < 32; o <<= 1) qv += __shfl_xor(qv, o, 32);
            float rs = rsqrtf(qv * (1.f / 64.f) + EPS);
            float y0 = dx * rs * g1[2 * cc] + be1[2 * cc];
            float y1 = dy * rs * g1[2 * cc + 1] + be1[2 * cc + 1];
            acc[tl][2 * cc]     = y0 > 0.f ? y0 : 0.f;
            acc[tl][2 * cc + 1] = y1 > 0.f ? y1 : 0.f;
        }
    }
    __syncthreads();

    // proj2 phase: p2 = y@Wl2, r2 = y@Wr2 + bl2
#pragma unroll
    for (int rnd = 0; rnd < 8; rnd++) {
        int tl = rnd * 8 + grp;
        int n = base + tl;
        if (n < N) {
            const float* yr = acc[tl];
            float ap = 0.f, ar = 0.f;
#pragma unroll 4
            for (int k = 0; k < 64; k++) {
                float y = yr[k];
                ap += y * Wlds[k * 32 + cc];
                ar += y * Wlds[2048 + k * 32 + cc];
            }
            p2h[(size_t)n * 32 + cc] = __float2half_rn(ap);
            r2h[(size_t)n * 32 + cc] = __float2half_rn(ar + bl2[cc]);
        }
    }
}

// ---------------- windowed aggregation layer 2 + output MLP (32 ch) ----------------
__global__ __launch_bounds__(256) void k_agg2w(const __half2* __restrict__ p2v,
                                               const __half2* __restrict__ r2v,
                                               const int* __restrict__ wrow,
                                               const int* __restrict__ col,
                                               const float* __restrict__ g2,
                                               const float* __restrict__ be2,
                                               const float* __restrict__ Wo1,
                                               const float* __restrict__ bo1,
                                               const float* __restrict__ Wo2,
                                               const float* __restrict__ bo2,
                                               float* __restrict__ out, int N) {
    __shared__ float acc[64][33];   // padded
    __shared__ float W1[32 * 16];
    __shared__ float b1s[16], w2s[16], b2s;
    __shared__ int cnt[64];
    int tid = threadIdx.x;
    for (int i = tid; i < 32 * 16; i += 256) W1[i] = Wo1[i];
    if (tid < 16) { b1s[tid] = bo1[tid]; w2s[tid] = Wo2[tid]; }
    if (tid == 0) b2s = bo2[0];
    for (int i = tid; i < 64 * 33; i += 256) ((float*)acc)[i] = 0.f;
    if (tid < 64) cnt[tid] = 0;
    __syncthreads();

    int wb = blockIdx.x;
    int base = wb << 6;
    int s0 = wrow[wb], s1 = wrow[wb + 1];
    int lane = tid & 15;
    int g = tid >> 4;   // 16 groups of 16 lanes

    int e = s0 + g;
    for (; e + 16 < s1; e += 32) {
        int pk0 = col[e];
        int pk1 = col[e + 16];
        int sA = pk0 >> 6, tA = pk0 & 63;
        int sB = pk1 >> 6, tB = pk1 & 63;
        float2 vA = __half22float2(p2v[(size_t)sA * 16 + lane]);
        float2 vB = __half22float2(p2v[(size_t)sB * 16 + lane]);
        atomicAdd(&acc[tA][2 * lane], vA.x);
        atomicAdd(&acc[tA][2 * lane + 1], vA.y);
        atomicAdd(&acc[tB][2 * lane], vB.x);
        atomicAdd(&acc[tB][2 * lane + 1], vB.y);
        if (lane == 0) { atomicAdd(&cnt[tA], 1); atomicAdd(&cnt[tB], 1); }
    }
    if (e < s1) {
        int pk0 = col[e];
        int sA = pk0 >> 6, tA = pk0 & 63;
        float2 vA = __half22float2(p2v[(size_t)sA * 16 + lane]);
        atomicAdd(&acc[tA][2 * lane], vA.x);
        atomicAdd(&acc[tA][2 * lane + 1], vA.y);
        if (lane == 0) atomicAdd(&cnt[tA], 1);
    }
    __syncthreads();

    // LN phase: 4 rounds x 16 groups; y overwrites acc rows
    int l = tid & 15;
    int grp = tid >> 4;
#pragma unroll
    for (int rnd = 0; rnd < 4; rnd++) {
        int tl = rnd * 16 + grp;
        int n = base + tl;
        if (n < N) {
            int c = cnt[tl];
            float inv = 1.f / (float)(c > 1 ? c : 1);
            float2 rr = __half22float2(r2v[(size_t)n * 16 + l]);
            float vx = acc[tl][2 * l] * inv + rr.x;
            float vy = acc[tl][2 * l + 1] * inv + rr.y;
            float s = vx + vy;
#pragma unroll
            for (int o = 1; o < 16; o <<= 1) s += __shfl_xor(s, o, 16);
            float m = s * (1.f / 32.f);
            float dx = vx - m, dy = vy - m;
            float qv = dx * dx + dy * dy;
#pragma unroll
            for (int o = 1; o < 16; o <<= 1) qv += __shfl_xor(qv, o, 16);
            float rs = rsqrtf(qv * (1.f / 32.f) + EPS);
            float y0 = dx * rs * g2[2 * l] + be2[2 * l];
            float y1 = dy * rs * g2[2 * l + 1] + be2[2 * l + 1];
            acc[tl][2 * l]     = y0 > 0.f ? y0 : 0.f;
            acc[tl][2 * l + 1] = y1 > 0.f ? y1 : 0.f;
        }
    }
    __syncthreads();

    // output MLP: a = relu(y@Wo1+bo1); out = a@Wo2 + bo2
#pragma unroll
    for (int rnd = 0; rnd < 4; rnd++) {
        int tl = rnd * 16 + grp;
        int n = base + tl;
        if (n < N) {
            const float* yr = acc[tl];
            float a = b1s[l];
#pragma unroll
            for (int k = 0; k < 32; k++) a += yr[k] * W1[k * 16 + l];
            a = a > 0.f ? a : 0.f;
            float contrib = a * w2s[l];
#pragma unroll
            for (int o = 1; o < 16; o <<= 1) contrib += __shfl_xor(contrib, o, 16);
            if (l == 0) out[n] = contrib + b2s;
        }
    }
}

extern "C" void kernel_launch(void* const* d_in, const int* in_sizes, int n_in,
                              void* d_out, int out_size, void* d_ws, size_t ws_size,
                              hipStream_t stream) {
    const float* x    = (const float*)d_in[0];
    const int*   ei   = (const int*)d_in[1];
    const float* W_in = (const float*)d_in[2];
    const float* b_in = (const float*)d_in[3];
    const float* Wl1  = (const float*)d_in[4];
    const float* bl1  = (const float*)d_in[5];
    const float* Wr1  = (const float*)d_in[6];
    const float* g1   = (const float*)d_in[7];
    const float* be1  = (const float*)d_in[8];
    const float* Wl2  = (const float*)d_in[9];
    const float* bl2  = (const float*)d_in[10];
    const float* Wr2  = (const float*)d_in[11];
    const float* g2   = (const float*)d_in[12];
    const float* be2  = (const float*)d_in[13];
    const float* Wo1  = (const float*)d_in[14];
    const float* bo1  = (const float*)d_in[15];
    const float* Wo2  = (const float*)d_in[16];
    const float* bo2  = (const float*)d_in[17];
    float* out = (float*)d_out;

    const int N = NN, E = NE;
    const int* src = ei;
    const int* tgt = ei + E;

    // workspace layout
    char* w = (char*)d_ws;
    int* wh   = (int*)w;  w += (size_t)NW * 4;
    int* wrow = (int*)w;  w += (size_t)(NW + 1) * 4;
    int* wcur = (int*)w;  w += (size_t)NW * 4;
    w = (char*)(((uintptr_t)w + 15) & ~(uintptr_t)15);
    int* col  = (int*)w;  w += (size_t)E * 4;
    f16* p1h  = (f16*)w;  w += (size_t)N * 64 * 2;
    f16* r1h  = (f16*)w;  w += (size_t)N * 64 * 2;
    f16* p2h  = (f16*)w;  w += (size_t)N * 32 * 2;
    f16* r2h  = (f16*)w;  w += (size_t)N * 32 * 2;
    f16* WinT = (f16*)w;  w += (size_t)128 * 104 * 2;
    f16* W2T  = (f16*)w;  w += (size_t)128 * 136 * 2;

    // ---- window partition build ----
    k_zero<<<4, 256, 0, stream>>>(wh, NW);
    k_whist<<<WFB, 256, 0, stream>>>(tgt, wh, E / 4);
    k_wscan<<<1, 256, 0, stream>>>(wh, wrow, wcur, NW);
    k_wfill<<<WFB, 256, 0, stream>>>(src, tgt, wcur, col);

    // ---- dense pipeline ----
    k_prep<<<68, 256, 0, stream>>>(W_in, Wl1, Wr1, WinT, W2T);
    k_in_proj1<<<(N + 31) / 32, 256, 0, stream>>>(x, WinT, b_in, W2T, bl1, p1h, r1h, N);
    k_agg1w<<<NW, 256, 0, stream>>>((const __half2*)p1h, (const __half2*)r1h, wrow, col,
                                    g1, be1, Wl2, Wr2, bl2, (__half*)p2h, (__half*)r2h, N);
    k_agg2w<<<NW, 256, 0, stream>>>((const __half2*)p2h, (const __half2*)r2h, wrow, col,
                                    g2, be2, Wo1, bo1, Wo2, bo2, out, N);
}

// Round 7
// 128.970 us; speedup vs baseline: 4.7555x; 4.7555x over previous
//
#include <hip/hip_runtime.h>
#include <hip/hip_bf16.h>
#include <hip/hip_fp16.h>

#define NN 50000
#define NE 800000
#define EPS 1e-5f
#define NW 782            // ceil(NN/64) windows of 64 nodes
#define WFB 100           // wfill/whist blocks
#define CHUNK (NE / WFB)  // 8000 edges per wfill block
#define CAP 2560          // LDS sort buffer (window mean 1023, 48 sigma headroom)

typedef _Float16 f16;
typedef _Float16 f16x8 __attribute__((ext_vector_type(8)));
typedef float f32x4 __attribute__((ext_vector_type(4)));

// ---------------- window partition build ----------------

__global__ void k_zero(int* __restrict__ p, int n) {
    int i = blockIdx.x * blockDim.x + threadIdx.x;
    for (; i < n; i += gridDim.x * blockDim.x) p[i] = 0;
}

// window histogram: LDS-merged then one global atomic per (block,window)
__global__ __launch_bounds__(256) void k_whist(const int* __restrict__ tgt,
                                               int* __restrict__ wh, int E4) {
    __shared__ int lh[NW];
    int tid = threadIdx.x;
    for (int i = tid; i < NW; i += 256) lh[i] = 0;
    __syncthreads();
    for (int i = blockIdx.x * 256 + tid; i < E4; i += gridDim.x * 256) {
        int4 t = ((const int4*)tgt)[i];
        atomicAdd(&lh[t.x >> 6], 1);
        atomicAdd(&lh[t.y >> 6], 1);
        atomicAdd(&lh[t.z >> 6], 1);
        atomicAdd(&lh[t.w >> 6], 1);
    }
    __syncthreads();
    for (int i = tid; i < NW; i += 256) {
        int c = lh[i];
        if (c) atomicAdd(&wh[i], c);
    }
}

__device__ __forceinline__ int waveInclScan(int v, int lane) {
#pragma unroll
    for (int o = 1; o < 64; o <<= 1) {
        int t = __shfl_up(v, o, 64);
        if (lane >= o) v += t;
    }
    return v;
}

// single-block carry scan over NW values -> wrow[0..NW], wcur copy; rowstart[NN] = E
__global__ __launch_bounds__(256) void k_wscan(const int* __restrict__ wh,
                                               int* __restrict__ wrow,
                                               int* __restrict__ wcur,
                                               int* __restrict__ rowstart, int n) {
    __shared__ int buf[256];
    __shared__ int carry_s;
    int tid = threadIdx.x;
    if (tid == 0) carry_s = 0;
    __syncthreads();
    for (int base = 0; base < n; base += 256) {
        int i = base + tid;
        int v = (i < n) ? wh[i] : 0;
        buf[tid] = v;
        __syncthreads();
        for (int off = 1; off < 256; off <<= 1) {
            int t = (tid >= off) ? buf[tid - off] : 0;
            __syncthreads();
            buf[tid] += t;
            __syncthreads();
        }
        int excl = buf[tid] - v;
        int c = carry_s;
        if (i < n) { wrow[i] = c + excl; wcur[i] = c + excl; }
        __syncthreads();
        if (tid == 0) carry_s = c + buf[255];
        __syncthreads();
    }
    if (tid == 0) { wrow[n] = carry_s; rowstart[NN] = carry_s; }
}

// partition edges into window spans (span-reservation: low write amplification)
__global__ __launch_bounds__(256) void k_wfill(const int* __restrict__ src,
                                               const int* __restrict__ tgt,
                                               int* __restrict__ wcur,
                                               int* __restrict__ colw) {
    __shared__ int lh[NW];
    __shared__ int sb[NW];
    int tid = threadIdx.x;
    int e0 = blockIdx.x * CHUNK;
    int i4hi = (e0 + CHUNK) >> 2;
    for (int i = tid; i < NW; i += 256) lh[i] = 0;
    __syncthreads();
#pragma unroll
    for (int j = 0; j < 8; j++) {
        int i4 = (e0 >> 2) + j * 256 + tid;
        if (i4 < i4hi) {
            int4 t = ((const int4*)tgt)[i4];
            atomicAdd(&lh[t.x >> 6], 1);
            atomicAdd(&lh[t.y >> 6], 1);
            atomicAdd(&lh[t.z >> 6], 1);
            atomicAdd(&lh[t.w >> 6], 1);
        }
    }
    __syncthreads();
    for (int i = tid; i < NW; i += 256) {
        int c = lh[i];
        sb[i] = c ? atomicAdd(&wcur[i], c) : 0;
        lh[i] = 0;
    }
    __syncthreads();
#pragma unroll
    for (int j = 0; j < 8; j++) {
        int i4 = (e0 >> 2) + j * 256 + tid;
        if (i4 < i4hi) {
            int4 t = ((const int4*)tgt)[i4];
            int4 s = ((const int4*)src)[i4];
            int w0 = t.x >> 6, r0 = atomicAdd(&lh[w0], 1);
            colw[sb[w0] + r0] = (s.x << 6) | (t.x & 63);
            int w1 = t.y >> 6, r1 = atomicAdd(&lh[w1], 1);
            colw[sb[w1] + r1] = (s.y << 6) | (t.y & 63);
            int w2 = t.z >> 6, r2 = atomicAdd(&lh[w2], 1);
            colw[sb[w2] + r2] = (s.z << 6) | (t.z & 63);
            int w3 = t.w >> 6, r3 = atomicAdd(&lh[w3], 1);
            colw[sb[w3] + r3] = (s.w << 6) | (t.w & 63);
        }
    }
}

// per-window LDS counting sort -> node-level CSR (rowstart, colsorted)
// one block per window; all global writes coalesced.
__global__ __launch_bounds__(256) void k_sort(const int* __restrict__ wrow,
                                              const int* __restrict__ colw,
                                              int* __restrict__ rowstart,
                                              int* __restrict__ colsorted, int N) {
    __shared__ int cnt[64], cur[64];
    __shared__ int sorted[CAP];
    int wb = blockIdx.x, tid = threadIdx.x;
    int s0 = wrow[wb], s1 = wrow[wb + 1];
    int len = s1 - s0;
    if (tid < 64) cnt[tid] = 0;
    __syncthreads();
    for (int i = s0 + tid; i < s1; i += 256) atomicAdd(&cnt[colw[i] & 63], 1);
    __syncthreads();
    if (tid < 64) {
        int v = cnt[tid];
        int incl = waveInclScan(v, tid);
        cur[tid] = incl - v;
        int n = (wb << 6) + tid;
        if (n < N) rowstart[n] = s0 + incl - v;
    }
    __syncthreads();
    if (len <= CAP) {
        for (int i = s0 + tid; i < s1; i += 256) {
            int pk = colw[i];
            int pos = atomicAdd(&cur[pk & 63], 1);
            sorted[pos] = pk >> 6;
        }
        __syncthreads();
        for (int i = tid; i < len; i += 256) colsorted[s0 + i] = sorted[i];
    } else {   // overflow fallback (never for this input)
        for (int i = s0 + tid; i < s1; i += 256) {
            int pk = colw[i];
            int pos = atomicAdd(&cur[pk & 63], 1);
            colsorted[s0 + pos] = pk >> 6;
        }
    }
}

// ---------------- weight prep (once, tiny) ----------------
__global__ __launch_bounds__(256) void k_prep(const float* __restrict__ Win,
                                              const float* __restrict__ Wl,
                                              const float* __restrict__ Wr,
                                              f16* __restrict__ WinT,
                                              f16* __restrict__ W2T) {
    int i0 = blockIdx.x * 256 + threadIdx.x;
    for (int i = i0; i < 128 * 104; i += gridDim.x * 256) {
        int c = i / 104, k = i - c * 104;
        float v = (k < 84) ? Win[k * 128 + c] : 0.f;
        WinT[c * 104 + k] = (f16)v;
    }
    for (int i = i0; i < 128 * 136; i += gridDim.x * 256) {
        int c = i / 136, k = i - c * 136;
        float v = 0.f;
        if (k < 128) v = (c < 64) ? Wl[k * 64 + c] : Wr[k * 64 + (c - 64)];
        W2T[c * 136 + k] = (f16)v;
    }
}

// ---------------- MFMA fused input stage ----------------
__global__ __launch_bounds__(256) void k_in_proj1(const float* __restrict__ x,
                                                  const f16* __restrict__ WinT,
                                                  const float* __restrict__ bin,
                                                  const f16* __restrict__ W2T,
                                                  const float* __restrict__ bl,
                                                  f16* __restrict__ p1h,
                                                  f16* __restrict__ r1h, int N) {
    __shared__ __align__(16) f16 xs[32 * 104];
    __shared__ __align__(16) f16 hs[32 * 136];
    int tid = threadIdx.x;
    int node0 = blockIdx.x * 32;
    int lane = tid & 63;
    int wv = tid >> 6;
    int r = lane & 15;
    int q = lane >> 4;

    f16x8 b1[2][3];
#pragma unroll
    for (int nt = 0; nt < 2; nt++) {
        int c = (2 * wv + nt) * 16 + r;
#pragma unroll
        for (int ks = 0; ks < 3; ks++)
            b1[nt][ks] = *(const f16x8*)&WinT[c * 104 + ks * 32 + q * 8];
    }
    for (int i = tid; i < 32 * 96; i += 256) {
        int nd = i / 96, k = i - nd * 96;
        int g = node0 + nd;
        float v = (g < N && k < 84) ? x[(size_t)g * 84 + k] : 0.f;
        xs[nd * 104 + k] = (f16)v;
    }
    __syncthreads();

    f32x4 acc[2][2] = {};
#pragma unroll
    for (int ks = 0; ks < 3; ks++) {
        int k0 = ks * 32;
        f16x8 a[2];
#pragma unroll
        for (int mt = 0; mt < 2; mt++)
            a[mt] = *(const f16x8*)&xs[(mt * 16 + r) * 104 + k0 + q * 8];
#pragma unroll
        for (int mt = 0; mt < 2; mt++)
#pragma unroll
            for (int nt = 0; nt < 2; nt++)
                acc[mt][nt] = __builtin_amdgcn_mfma_f32_16x16x32_f16(a[mt], b1[nt][ks], acc[mt][nt], 0, 0, 0);
    }

    f16x8 b2[2][4];
#pragma unroll
    for (int nt = 0; nt < 2; nt++) {
        int c = (2 * wv + nt) * 16 + r;
#pragma unroll
        for (int ks = 0; ks < 4; ks++)
            b2[nt][ks] = *(const f16x8*)&W2T[c * 136 + ks * 32 + q * 8];
    }

#pragma unroll
    for (int nt = 0; nt < 2; nt++) {
        int c = (2 * wv + nt) * 16 + r;
        float bb = bin[c];
#pragma unroll
        for (int mt = 0; mt < 2; mt++)
#pragma unroll
            for (int v = 0; v < 4; v++) {
                int row = mt * 16 + q * 4 + v;
                float val = acc[mt][nt][v] + bb;
                hs[row * 136 + c] = (f16)(val > 0.f ? val : 0.f);
            }
    }
    __syncthreads();

    f32x4 acc2[2][2] = {};
#pragma unroll
    for (int ks = 0; ks < 4; ks++) {
        int k0 = ks * 32;
        f16x8 a[2];
#pragma unroll
        for (int mt = 0; mt < 2; mt++)
            a[mt] = *(const f16x8*)&hs[(mt * 16 + r) * 136 + k0 + q * 8];
#pragma unroll
        for (int mt = 0; mt < 2; mt++)
#pragma unroll
            for (int nt = 0; nt < 2; nt++)
                acc2[mt][nt] = __builtin_amdgcn_mfma_f32_16x16x32_f16(a[mt], b2[nt][ks], acc2[mt][nt], 0, 0, 0);
    }

#pragma unroll
    for (int nt = 0; nt < 2; nt++) {
        int c = (2 * wv + nt) * 16 + r;
        float bb = (c >= 64) ? bl[c - 64] : 0.f;
#pragma unroll
        for (int mt = 0; mt < 2; mt++)
#pragma unroll
            for (int v = 0; v < 4; v++) {
                int n = node0 + mt * 16 + q * 4 + v;
                if (n < N) {
                    float val = acc2[mt][nt][v];
                    if (c < 64) p1h[(size_t)n * 64 + c] = (f16)val;
                    else        r1h[(size_t)n * 64 + (c - 64)] = (f16)(val + bb);
                }
            }
    }
}

// (p1 fp16, r1 fp16, CSR) -> p2 (fp16), r2 (fp16): mean-agg + LN + relu then proj2.
// 8 nodes/block, 32 lanes per node, 4-deep gather pipeline.
__global__ __launch_bounds__(256) void k_agg1_proj2(const __half2* __restrict__ p1v,
                                                    const __half2* __restrict__ r1v,
                                                    const int* __restrict__ rowstart,
                                                    const int* __restrict__ col,
                                                    const float* __restrict__ g1,
                                                    const float* __restrict__ be1,
                                                    const float* __restrict__ Wl2,
                                                    const float* __restrict__ Wr2,
                                                    const float* __restrict__ bl2,
                                                    __half* __restrict__ p2h,
                                                    __half* __restrict__ r2h, int N) {
    __shared__ float Wlds[2 * 2048];   // 16 KB: Wl2 | Wr2
    __shared__ float ylds[8][64];
    int tid = threadIdx.x;
    for (int i = tid; i < 2048; i += 256) {
        Wlds[i] = Wl2[i];
        Wlds[2048 + i] = Wr2[i];
    }
    int cc = tid & 31;
    int grp = tid >> 5;
    int n = blockIdx.x * 8 + grp;
    if (n < N) {
        int s0 = rowstart[n], s1 = rowstart[n + 1];
        float2 a0 = make_float2(0.f, 0.f), a1 = a0, a2 = a0, a3 = a0;
        int i = s0;
        for (; i + 3 < s1; i += 4) {
            float2 v0 = __half22float2(p1v[(size_t)col[i]     * 32 + cc]);
            float2 v1 = __half22float2(p1v[(size_t)col[i + 1] * 32 + cc]);
            float2 v2 = __half22float2(p1v[(size_t)col[i + 2] * 32 + cc]);
            float2 v3 = __half22float2(p1v[(size_t)col[i + 3] * 32 + cc]);
            a0.x += v0.x; a0.y += v0.y;
            a1.x += v1.x; a1.y += v1.y;
            a2.x += v2.x; a2.y += v2.y;
            a3.x += v3.x; a3.y += v3.y;
        }
        for (; i < s1; i++) {
            float2 v0 = __half22float2(p1v[(size_t)col[i] * 32 + cc]);
            a0.x += v0.x; a0.y += v0.y;
        }
        float sx = a0.x + a1.x + a2.x + a3.x;
        float sy = a0.y + a1.y + a2.y + a3.y;
        int cnt = s1 - s0;
        float inv = 1.f / (float)(cnt > 1 ? cnt : 1);
        float2 rr = __half22float2(r1v[(size_t)n * 32 + cc]);
        float vx = sx * inv + rr.x;
        float vy = sy * inv + rr.y;
        float s = vx + vy;
#pragma unroll
        for (int o = 1; o < 32; o <<= 1) s += __shfl_xor(s, o, 32);
        float m = s * (1.f / 64.f);
        float dx = vx - m, dy = vy - m;
        float qv = dx * dx + dy * dy;
#pragma unroll
        for (int o = 1; o < 32; o <<= 1) qv += __shfl_xor(qv, o, 32);
        float rs = rsqrtf(qv * (1.f / 64.f) + EPS);
        float y0 = dx * rs * g1[2 * cc] + be1[2 * cc];
        float y1 = dy * rs * g1[2 * cc + 1] + be1[2 * cc + 1];
        ylds[grp][2 * cc]     = y0 > 0.f ? y0 : 0.f;
        ylds[grp][2 * cc + 1] = y1 > 0.f ? y1 : 0.f;
    }
    __syncthreads();
    if (n < N) {
        const float* yr = ylds[grp];
        float ap = 0.f, ar = 0.f;
#pragma unroll 4
        for (int k = 0; k < 64; k++) {
            float y = yr[k];
            ap += y * Wlds[k * 32 + cc];
            ar += y * Wlds[2048 + k * 32 + cc];
        }
        p2h[(size_t)n * 32 + cc] = __float2half_rn(ap);
        r2h[(size_t)n * 32 + cc] = __float2half_rn(ar + bl2[cc]);
    }
}

// (p2 fp16, r2 fp16, CSR) -> out : mean-agg + LN + relu + 2-layer MLP.
// 16 nodes/block, 16 lanes per node.
__global__ __launch_bounds__(256) void k_agg2_out(const __half2* __restrict__ p2v,
                                                  const __half2* __restrict__ r2v,
                                                  const int* __restrict__ rowstart,
                                                  const int* __restrict__ col,
                                                  const float* __restrict__ g2,
                                                  const float* __restrict__ be2,
                                                  const float* __restrict__ Wo1,
                                                  const float* __restrict__ bo1,
                                                  const float* __restrict__ Wo2,
                                                  const float* __restrict__ bo2,
                                                  float* __restrict__ out, int N) {
    __shared__ float W1[32 * 16];
    __shared__ float ylds[16][32];
    __shared__ float b1s[16], w2s[16], b2s;
    int tid = threadIdx.x;
    for (int i = tid; i < 32 * 16; i += 256) W1[i] = Wo1[i];
    if (tid < 16) { b1s[tid] = bo1[tid]; w2s[tid] = Wo2[tid]; }
    if (tid == 0) b2s = bo2[0];
    int l = tid & 15;
    int grp = tid >> 4;
    int n = blockIdx.x * 16 + grp;
    if (n < N) {
        int s0 = rowstart[n], s1 = rowstart[n + 1];
        float2 a0 = make_float2(0.f, 0.f), a1 = a0, a2 = a0, a3 = a0;
        int i = s0;
        for (; i + 3 < s1; i += 4) {
            float2 v0 = __half22float2(p2v[(size_t)col[i]     * 16 + l]);
            float2 v1 = __half22float2(p2v[(size_t)col[i + 1] * 16 + l]);
            float2 v2 = __half22float2(p2v[(size_t)col[i + 2] * 16 + l]);
            float2 v3 = __half22float2(p2v[(size_t)col[i + 3] * 16 + l]);
            a0.x += v0.x; a0.y += v0.y;
            a1.x += v1.x; a1.y += v1.y;
            a2.x += v2.x; a2.y += v2.y;
            a3.x += v3.x; a3.y += v3.y;
        }
        for (; i < s1; i++) {
            float2 v0 = __half22float2(p2v[(size_t)col[i] * 16 + l]);
            a0.x += v0.x; a0.y += v0.y;
        }
        float sx = a0.x + a1.x + a2.x + a3.x;
        float sy = a0.y + a1.y + a2.y + a3.y;
        int cnt = s1 - s0;
        float inv = 1.f / (float)(cnt > 1 ? cnt : 1);
        float2 rr = __half22float2(r2v[(size_t)n * 16 + l]);
        float vx = sx * inv + rr.x;
        float vy = sy * inv + rr.y;
        float s = vx + vy;
#pragma unroll
        for (int o = 1; o < 16; o <<= 1) s += __shfl_xor(s, o, 16);
        float m = s * (1.f / 32.f);
        float dx = vx - m, dy = vy - m;
        float qv = dx * dx + dy * dy;
#pragma unroll
        for (int o = 1; o < 16; o <<= 1) qv += __shfl_xor(qv, o, 16);
        float rs = rsqrtf(qv * (1.f / 32.f) + EPS);
        float y0 = dx * rs * g2[2 * l] + be2[2 * l];
        float y1 = dy * rs * g2[2 * l + 1] + be2[2 * l + 1];
        ylds[grp][2 * l]     = y0 > 0.f ? y0 : 0.f;
        ylds[grp][2 * l + 1] = y1 > 0.f ? y1 : 0.f;
    }
    __syncthreads();
    if (n < N) {
        const float* yr = ylds[grp];
        float a = b1s[l];
#pragma unroll
        for (int k = 0; k < 32; k++) a += yr[k] * W1[k * 16 + l];
        a = a > 0.f ? a : 0.f;
        float contrib = a * w2s[l];
#pragma unroll
        for (int o = 1; o < 16; o <<= 1) contrib += __shfl_xor(contrib, o, 16);
        if (l == 0) out[n] = contrib + b2s;
    }
}

extern "C" void kernel_launch(void* const* d_in, const int* in_sizes, int n_in,
                              void* d_out, int out_size, void* d_ws, size_t ws_size,
                              hipStream_t stream) {
    const float* x    = (const float*)d_in[0];
    const int*   ei   = (const int*)d_in[1];
    const float* W_in = (const float*)d_in[2];
    const float* b_in = (const float*)d_in[3];
    const float* Wl1  = (const float*)d_in[4];
    const float* bl1  = (const float*)d_in[5];
    const float* Wr1  = (const float*)d_in[6];
    const float* g1   = (const float*)d_in[7];
    const float* be1  = (const float*)d_in[8];
    const float* Wl2  = (const float*)d_in[9];
    const float* bl2  = (const float*)d_in[10];
    const float* Wr2  = (const float*)d_in[11];
    const float* g2   = (const float*)d_in[12];
    const float* be2  = (const float*)d_in[13];
    const float* Wo1  = (const float*)d_in[14];
    const float* bo1  = (const float*)d_in[15];
    const float* Wo2  = (const float*)d_in[16];
    const float* bo2  = (const float*)d_in[17];
    float* out = (float*)d_out;

    const int N = NN, E = NE;
    const int* src = ei;
    const int* tgt = ei + E;

    // workspace layout
    char* w = (char*)d_ws;
    int* wh       = (int*)w;  w += (size_t)NW * 4;
    int* wrow     = (int*)w;  w += (size_t)(NW + 1) * 4;
    int* wcur     = (int*)w;  w += (size_t)NW * 4;
    int* rowstart = (int*)w;  w += (size_t)(NN + 1) * 4;
    w = (char*)(((uintptr_t)w + 15) & ~(uintptr_t)15);
    int* colw     = (int*)w;  w += (size_t)E * 4;
    int* colsort  = (int*)w;  w += (size_t)E * 4;
    f16* p1h  = (f16*)w;  w += (size_t)N * 64 * 2;
    f16* r1h  = (f16*)w;  w += (size_t)N * 64 * 2;
    f16* p2h  = (f16*)w;  w += (size_t)N * 32 * 2;
    f16* r2h  = (f16*)w;  w += (size_t)N * 32 * 2;
    f16* WinT = (f16*)w;  w += (size_t)128 * 104 * 2;
    f16* W2T  = (f16*)w;  w += (size_t)128 * 136 * 2;

    // ---- window partition + node CSR via per-window counting sort ----
    k_zero<<<4, 256, 0, stream>>>(wh, NW);
    k_whist<<<WFB, 256, 0, stream>>>(tgt, wh, E / 4);
    k_wscan<<<1, 256, 0, stream>>>(wh, wrow, wcur, rowstart, NW);
    k_wfill<<<WFB, 256, 0, stream>>>(src, tgt, wcur, colw);
    k_sort<<<NW, 256, 0, stream>>>(wrow, colw, rowstart, colsort, N);

    // ---- dense pipeline ----
    k_prep<<<68, 256, 0, stream>>>(W_in, Wl1, Wr1, WinT, W2T);
    k_in_proj1<<<(N + 31) / 32, 256, 0, stream>>>(x, WinT, b_in, W2T, bl1, p1h, r1h, N);
    k_agg1_proj2<<<(N + 7) / 8, 256, 0, stream>>>((const __half2*)p1h, (const __half2*)r1h,
                                                  rowstart, colsort, g1, be1,
                                                  Wl2, Wr2, bl2, (__half*)p2h, (__half*)r2h, N);
    k_agg2_out<<<(N + 15) / 16, 256, 0, stream>>>((const __half2*)p2h, (const __half2*)r2h,
                                                  rowstart, colsort, g2, be2,
                                                  Wo1, bo1, Wo2, bo2, out, N);
}

// Round 8
// 118.654 us; speedup vs baseline: 5.1690x; 1.0869x over previous
//
#include <hip/hip_runtime.h>
#include <hip/hip_bf16.h>
#include <hip/hip_fp16.h>

#define NN 50000
#define NE 800000
#define EPS 1e-5f
#define NW 782            // ceil(NN/64) windows of 64 nodes
#define WFB 200           // wfill blocks
#define CHUNK (NE / WFB)  // 4000 edges per wfill block
#define CAP 2560          // LDS sort buffer
#define PREPB 64          // prep blocks in fused A
#define INPB ((NN + 31) / 32)   // 1563 in_proj1 blocks in fused B

typedef _Float16 f16;
typedef _Float16 f16x8 __attribute__((ext_vector_type(8)));
typedef float f32x4 __attribute__((ext_vector_type(4)));

__device__ __forceinline__ int waveInclScan(int v, int lane) {
#pragma unroll
    for (int o = 1; o < 64; o <<= 1) {
        int t = __shfl_up(v, o, 64);
        if (lane >= o) v += t;
    }
    return v;
}

// ---------------- fused A: weight prep (blocks <PREPB) | window hist (rest) ----------------
__global__ __launch_bounds__(256) void k_prep_whist(const float* __restrict__ Win,
                                                    const float* __restrict__ Wl,
                                                    const float* __restrict__ Wr,
                                                    f16* __restrict__ WinT,
                                                    f16* __restrict__ W2T,
                                                    const int* __restrict__ tgt,
                                                    int* __restrict__ wh, int E4) {
    __shared__ int lh[NW];
    int tid = threadIdx.x;
    if (blockIdx.x < PREPB) {
        int i0 = blockIdx.x * 256 + tid;
        for (int i = i0; i < 128 * 104; i += PREPB * 256) {
            int c = i / 104, k = i - c * 104;
            float v = (k < 84) ? Win[k * 128 + c] : 0.f;
            WinT[c * 104 + k] = (f16)v;
        }
        for (int i = i0; i < 128 * 136; i += PREPB * 256) {
            int c = i / 136, k = i - c * 136;
            float v = 0.f;
            if (k < 128) v = (c < 64) ? Wl[k * 64 + c] : Wr[k * 64 + (c - 64)];
            W2T[c * 136 + k] = (f16)v;
        }
    } else {
        int bid = blockIdx.x - PREPB;
        int nb = gridDim.x - PREPB;
        for (int i = tid; i < NW; i += 256) lh[i] = 0;
        __syncthreads();
        for (int i = bid * 256 + tid; i < E4; i += nb * 256) {
            int4 t = ((const int4*)tgt)[i];
            atomicAdd(&lh[t.x >> 6], 1);
            atomicAdd(&lh[t.y >> 6], 1);
            atomicAdd(&lh[t.z >> 6], 1);
            atomicAdd(&lh[t.w >> 6], 1);
        }
        __syncthreads();
        for (int i = tid; i < NW; i += 256) {
            int c = lh[i];
            if (c) atomicAdd(&wh[i], c);
        }
    }
}

// single-block carry scan over NW values -> wrow[0..NW], wcur copy; rowstart[NN] = E
__global__ __launch_bounds__(256) void k_wscan(const int* __restrict__ wh,
                                               int* __restrict__ wrow,
                                               int* __restrict__ wcur,
                                               int* __restrict__ rowstart, int n) {
    __shared__ int buf[256];
    __shared__ int carry_s;
    int tid = threadIdx.x;
    if (tid == 0) carry_s = 0;
    __syncthreads();
    for (int base = 0; base < n; base += 256) {
        int i = base + tid;
        int v = (i < n) ? wh[i] : 0;
        buf[tid] = v;
        __syncthreads();
        for (int off = 1; off < 256; off <<= 1) {
            int t = (tid >= off) ? buf[tid - off] : 0;
            __syncthreads();
            buf[tid] += t;
            __syncthreads();
        }
        int excl = buf[tid] - v;
        int c = carry_s;
        if (i < n) { wrow[i] = c + excl; wcur[i] = c + excl; }
        __syncthreads();
        if (tid == 0) carry_s = c + buf[255];
        __syncthreads();
    }
    if (tid == 0) { wrow[n] = carry_s; rowstart[NN] = carry_s; }
}

// ---------------- fused B: wfill (blocks <WFB) | MFMA in_proj1 (rest) ----------------
__global__ __launch_bounds__(256) void k_wfill_inproj(const int* __restrict__ src,
                                                      const int* __restrict__ tgt,
                                                      int* __restrict__ wcur,
                                                      int* __restrict__ colw,
                                                      const float* __restrict__ x,
                                                      const f16* __restrict__ WinT,
                                                      const float* __restrict__ bin,
                                                      const f16* __restrict__ W2T,
                                                      const float* __restrict__ bl,
                                                      f16* __restrict__ p1h,
                                                      f16* __restrict__ r1h, int N) {
    __shared__ int lh[NW];
    __shared__ int sb[NW];
    __shared__ __align__(16) f16 xs[32 * 104];
    __shared__ __align__(16) f16 hs[32 * 136];
    int tid = threadIdx.x;

    if (blockIdx.x < WFB) {
        // ---- wfill: span-reserved window partition ----
        int i4lo = (blockIdx.x * CHUNK) >> 2;
        int i4hi = i4lo + (CHUNK >> 2);
        for (int i = tid; i < NW; i += 256) lh[i] = 0;
        __syncthreads();
        for (int i4 = i4lo + tid; i4 < i4hi; i4 += 256) {
            int4 t = ((const int4*)tgt)[i4];
            atomicAdd(&lh[t.x >> 6], 1);
            atomicAdd(&lh[t.y >> 6], 1);
            atomicAdd(&lh[t.z >> 6], 1);
            atomicAdd(&lh[t.w >> 6], 1);
        }
        __syncthreads();
        for (int i = tid; i < NW; i += 256) {
            int c = lh[i];
            sb[i] = c ? atomicAdd(&wcur[i], c) : 0;
            lh[i] = 0;
        }
        __syncthreads();
        for (int i4 = i4lo + tid; i4 < i4hi; i4 += 256) {
            int4 t = ((const int4*)tgt)[i4];
            int4 s = ((const int4*)src)[i4];
            int w0 = t.x >> 6, r0 = atomicAdd(&lh[w0], 1);
            colw[sb[w0] + r0] = (s.x << 6) | (t.x & 63);
            int w1 = t.y >> 6, r1 = atomicAdd(&lh[w1], 1);
            colw[sb[w1] + r1] = (s.y << 6) | (t.y & 63);
            int w2 = t.z >> 6, r2 = atomicAdd(&lh[w2], 1);
            colw[sb[w2] + r2] = (s.z << 6) | (t.z & 63);
            int w3 = t.w >> 6, r3 = atomicAdd(&lh[w3], 1);
            colw[sb[w3] + r3] = (s.w << 6) | (t.w & 63);
        }
        return;
    }

    // ---- in_proj1: x -> h1 (LDS) -> p1, r1 via MFMA ----
    int node0 = (blockIdx.x - WFB) * 32;
    int lane = tid & 63;
    int wv = tid >> 6;
    int r = lane & 15;
    int q = lane >> 4;

    f16x8 b1[2][3];
#pragma unroll
    for (int nt = 0; nt < 2; nt++) {
        int c = (2 * wv + nt) * 16 + r;
#pragma unroll
        for (int ks = 0; ks < 3; ks++)
            b1[nt][ks] = *(const f16x8*)&WinT[c * 104 + ks * 32 + q * 8];
    }
    for (int i = tid; i < 32 * 96; i += 256) {
        int nd = i / 96, k = i - nd * 96;
        int g = node0 + nd;
        float v = (g < N && k < 84) ? x[(size_t)g * 84 + k] : 0.f;
        xs[nd * 104 + k] = (f16)v;
    }
    __syncthreads();

    f32x4 acc[2][2] = {};
#pragma unroll
    for (int ks = 0; ks < 3; ks++) {
        int k0 = ks * 32;
        f16x8 a[2];
#pragma unroll
        for (int mt = 0; mt < 2; mt++)
            a[mt] = *(const f16x8*)&xs[(mt * 16 + r) * 104 + k0 + q * 8];
#pragma unroll
        for (int mt = 0; mt < 2; mt++)
#pragma unroll
            for (int nt = 0; nt < 2; nt++)
                acc[mt][nt] = __builtin_amdgcn_mfma_f32_16x16x32_f16(a[mt], b1[nt][ks], acc[mt][nt], 0, 0, 0);
    }

    f16x8 b2[2][4];
#pragma unroll
    for (int nt = 0; nt < 2; nt++) {
        int c = (2 * wv + nt) * 16 + r;
#pragma unroll
        for (int ks = 0; ks < 4; ks++)
            b2[nt][ks] = *(const f16x8*)&W2T[c * 136 + ks * 32 + q * 8];
    }

#pragma unroll
    for (int nt = 0; nt < 2; nt++) {
        int c = (2 * wv + nt) * 16 + r;
        float bb = bin[c];
#pragma unroll
        for (int mt = 0; mt < 2; mt++)
#pragma unroll
            for (int v = 0; v < 4; v++) {
                int row = mt * 16 + q * 4 + v;
                float val = acc[mt][nt][v] + bb;
                hs[row * 136 + c] = (f16)(val > 0.f ? val : 0.f);
            }
    }
    __syncthreads();

    f32x4 acc2[2][2] = {};
#pragma unroll
    for (int ks = 0; ks < 4; ks++) {
        int k0 = ks * 32;
        f16x8 a[2];
#pragma unroll
        for (int mt = 0; mt < 2; mt++)
            a[mt] = *(const f16x8*)&hs[(mt * 16 + r) * 136 + k0 + q * 8];
#pragma unroll
        for (int mt = 0; mt < 2; mt++)
#pragma unroll
            for (int nt = 0; nt < 2; nt++)
                acc2[mt][nt] = __builtin_amdgcn_mfma_f32_16x16x32_f16(a[mt], b2[nt][ks], acc2[mt][nt], 0, 0, 0);
    }

#pragma unroll
    for (int nt = 0; nt < 2; nt++) {
        int c = (2 * wv + nt) * 16 + r;
        float bb = (c >= 64) ? bl[c - 64] : 0.f;
#pragma unroll
        for (int mt = 0; mt < 2; mt++)
#pragma unroll
            for (int v = 0; v < 4; v++) {
                int n = node0 + mt * 16 + q * 4 + v;
                if (n < N) {
                    float val = acc2[mt][nt][v];
                    if (c < 64) p1h[(size_t)n * 64 + c] = (f16)val;
                    else        r1h[(size_t)n * 64 + (c - 64)] = (f16)(val + bb);
                }
            }
    }
}

// per-window LDS counting sort -> node-level CSR (rowstart, colsorted)
__global__ __launch_bounds__(256) void k_sort(const int* __restrict__ wrow,
                                              const int* __restrict__ colw,
                                              int* __restrict__ rowstart,
                                              int* __restrict__ colsorted, int N) {
    __shared__ int cnt[64], cur[64];
    __shared__ int sorted[CAP];
    int wb = blockIdx.x, tid = threadIdx.x;
    int s0 = wrow[wb], s1 = wrow[wb + 1];
    int len = s1 - s0;
    if (tid < 64) cnt[tid] = 0;
    __syncthreads();
    for (int i = s0 + tid; i < s1; i += 256) atomicAdd(&cnt[colw[i] & 63], 1);
    __syncthreads();
    if (tid < 64) {
        int v = cnt[tid];
        int incl = waveInclScan(v, tid);
        cur[tid] = incl - v;
        int n = (wb << 6) + tid;
        if (n < N) rowstart[n] = s0 + incl - v;
    }
    __syncthreads();
    if (len <= CAP) {
        for (int i = s0 + tid; i < s1; i += 256) {
            int pk = colw[i];
            int pos = atomicAdd(&cur[pk & 63], 1);
            sorted[pos] = pk >> 6;
        }
        __syncthreads();
        for (int i = tid; i < len; i += 256) colsorted[s0 + i] = sorted[i];
    } else {
        for (int i = s0 + tid; i < s1; i += 256) {
            int pk = colw[i];
            int pos = atomicAdd(&cur[pk & 63], 1);
            colsorted[s0 + pos] = pk >> 6;
        }
    }
}

#define F2ADD(a, b) { (a).x += (b).x; (a).y += (b).y; }

// (p1 fp16, r1 fp16, CSR) -> p2, r2 : mean-agg + LN + relu then proj2.
// 8 nodes/block, 32 lanes per node, 8-deep gather pipeline.
__global__ __launch_bounds__(256) void k_agg1_proj2(const __half2* __restrict__ p1v,
                                                    const __half2* __restrict__ r1v,
                                                    const int* __restrict__ rowstart,
                                                    const int* __restrict__ col,
                                                    const float* __restrict__ g1,
                                                    const float* __restrict__ be1,
                                                    const float* __restrict__ Wl2,
                                                    const float* __restrict__ Wr2,
                                                    const float* __restrict__ bl2,
                                                    __half* __restrict__ p2h,
                                                    __half* __restrict__ r2h, int N) {
    __shared__ float Wlds[2 * 2048];
    __shared__ float ylds[8][64];
    int tid = threadIdx.x;
    for (int i = tid; i < 2048; i += 256) {
        Wlds[i] = Wl2[i];
        Wlds[2048 + i] = Wr2[i];
    }
    unsigned cc = tid & 31;
    int grp = tid >> 5;
    int n = blockIdx.x * 8 + grp;
    if (n < N) {
        int s0 = rowstart[n], s1 = rowstart[n + 1];
        float2 a0 = make_float2(0.f, 0.f), a1 = a0, a2 = a0, a3 = a0;
        float2 a4 = a0, a5 = a0, a6 = a0, a7 = a0;
        int i = s0;
        for (; i + 7 < s1; i += 8) {
            unsigned c0 = col[i],     c1 = col[i + 1], c2 = col[i + 2], c3 = col[i + 3];
            unsigned c4 = col[i + 4], c5 = col[i + 5], c6 = col[i + 6], c7 = col[i + 7];
            float2 v0 = __half22float2(p1v[c0 * 32u + cc]);
            float2 v1 = __half22float2(p1v[c1 * 32u + cc]);
            float2 v2 = __half22float2(p1v[c2 * 32u + cc]);
            float2 v3 = __half22float2(p1v[c3 * 32u + cc]);
            float2 v4 = __half22float2(p1v[c4 * 32u + cc]);
            float2 v5 = __half22float2(p1v[c5 * 32u + cc]);
            float2 v6 = __half22float2(p1v[c6 * 32u + cc]);
            float2 v7 = __half22float2(p1v[c7 * 32u + cc]);
            F2ADD(a0, v0) F2ADD(a1, v1) F2ADD(a2, v2) F2ADD(a3, v3)
            F2ADD(a4, v4) F2ADD(a5, v5) F2ADD(a6, v6) F2ADD(a7, v7)
        }
        for (; i < s1; i++) {
            float2 v0 = __half22float2(p1v[(unsigned)col[i] * 32u + cc]);
            F2ADD(a0, v0)
        }
        F2ADD(a0, a4) F2ADD(a1, a5) F2ADD(a2, a6) F2ADD(a3, a7)
        F2ADD(a0, a2) F2ADD(a1, a3) F2ADD(a0, a1)
        int cnt = s1 - s0;
        float inv = 1.f / (float)(cnt > 1 ? cnt : 1);
        float2 rr = __half22float2(r1v[(unsigned)n * 32u + cc]);
        float vx = a0.x * inv + rr.x;
        float vy = a0.y * inv + rr.y;
        float s = vx + vy;
#pragma unroll
        for (int o = 1; o < 32; o <<= 1) s += __shfl_xor(s, o, 32);
        float m = s * (1.f / 64.f);
        float dx = vx - m, dy = vy - m;
        float qv = dx * dx + dy * dy;
#pragma unroll
        for (int o = 1; o < 32; o <<= 1) qv += __shfl_xor(qv, o, 32);
        float rs = rsqrtf(qv * (1.f / 64.f) + EPS);
        float y0 = dx * rs * g1[2 * cc] + be1[2 * cc];
        float y1 = dy * rs * g1[2 * cc + 1] + be1[2 * cc + 1];
        ylds[grp][2 * cc]     = y0 > 0.f ? y0 : 0.f;
        ylds[grp][2 * cc + 1] = y1 > 0.f ? y1 : 0.f;
    }
    __syncthreads();
    if (n < N) {
        const float* yr = ylds[grp];
        float ap = 0.f, ar = 0.f;
#pragma unroll 4
        for (int k = 0; k < 64; k++) {
            float y = yr[k];
            ap += y * Wlds[k * 32 + cc];
            ar += y * Wlds[2048 + k * 32 + cc];
        }
        p2h[(size_t)n * 32 + cc] = __float2half_rn(ap);
        r2h[(size_t)n * 32 + cc] = __float2half_rn(ar + bl2[cc]);
    }
}

// (p2 fp16, r2 fp16, CSR) -> out : mean-agg + LN + relu + 2-layer MLP.
// 16 nodes/block, 16 lanes per node, 8-deep gather pipeline.
__global__ __launch_bounds__(256) void k_agg2_out(const __half2* __restrict__ p2v,
                                                  const __half2* __restrict__ r2v,
                                                  const int* __restrict__ rowstart,
                                                  const int* __restrict__ col,
                                                  const float* __restrict__ g2,
                                                  const float* __restrict__ be2,
                                                  const float* __restrict__ Wo1,
                                                  const float* __restrict__ bo1,
                                                  const float* __restrict__ Wo2,
                                                  const float* __restrict__ bo2,
                                                  float* __restrict__ out, int N) {
    __shared__ float W1[32 * 16];
    __shared__ float ylds[16][32];
    __shared__ float b1s[16], w2s[16], b2s;
    int tid = threadIdx.x;
    for (int i = tid; i < 32 * 16; i += 256) W1[i] = Wo1[i];
    if (tid < 16) { b1s[tid] = bo1[tid]; w2s[tid] = Wo2[tid]; }
    if (tid == 0) b2s = bo2[0];
    unsigned l = tid & 15;
    int grp = tid >> 4;
    int n = blockIdx.x * 16 + grp;
    if (n < N) {
        int s0 = rowstart[n], s1 = rowstart[n + 1];
        float2 a0 = make_float2(0.f, 0.f), a1 = a0, a2 = a0, a3 = a0;
        float2 a4 = a0, a5 = a0, a6 = a0, a7 = a0;
        int i = s0;
        for (; i + 7 < s1; i += 8) {
            unsigned c0 = col[i],     c1 = col[i + 1], c2 = col[i + 2], c3 = col[i + 3];
            unsigned c4 = col[i + 4], c5 = col[i + 5], c6 = col[i + 6], c7 = col[i + 7];
            float2 v0 = __half22float2(p2v[c0 * 16u + l]);
            float2 v1 = __half22float2(p2v[c1 * 16u + l]);
            float2 v2 = __half22float2(p2v[c2 * 16u + l]);
            float2 v3 = __half22float2(p2v[c3 * 16u + l]);
            float2 v4 = __half22float2(p2v[c4 * 16u + l]);
            float2 v5 = __half22float2(p2v[c5 * 16u + l]);
            float2 v6 = __half22float2(p2v[c6 * 16u + l]);
            float2 v7 = __half22float2(p2v[c7 * 16u + l]);
            F2ADD(a0, v0) F2ADD(a1, v1) F2ADD(a2, v2) F2ADD(a3, v3)
            F2ADD(a4, v4) F2ADD(a5, v5) F2ADD(a6, v6) F2ADD(a7, v7)
        }
        for (; i < s1; i++) {
            float2 v0 = __half22float2(p2v[(unsigned)col[i] * 16u + l]);
            F2ADD(a0, v0)
        }
        F2ADD(a0, a4) F2ADD(a1, a5) F2ADD(a2, a6) F2ADD(a3, a7)
        F2ADD(a0, a2) F2ADD(a1, a3) F2ADD(a0, a1)
        int cnt = s1 - s0;
        float inv = 1.f / (float)(cnt > 1 ? cnt : 1);
        float2 rr = __half22float2(r2v[(unsigned)n * 16u + l]);
        float vx = a0.x * inv + rr.x;
        float vy = a0.y * inv + rr.y;
        float s = vx + vy;
#pragma unroll
        for (int o = 1; o < 16; o <<= 1) s += __shfl_xor(s, o, 16);
        float m = s * (1.f / 32.f);
        float dx = vx - m, dy = vy - m;
        float qv = dx * dx + dy * dy;
#pragma unroll
        for (int o = 1; o < 16; o <<= 1) qv += __shfl_xor(qv, o, 16);
        float rs = rsqrtf(qv * (1.f / 32.f) + EPS);
        float y0 = dx * rs * g2[2 * l] + be2[2 * l];
        float y1 = dy * rs * g2[2 * l + 1] + be2[2 * l + 1];
        ylds[grp][2 * l]     = y0 > 0.f ? y0 : 0.f;
        ylds[grp][2 * l + 1] = y1 > 0.f ? y1 : 0.f;
    }
    __syncthreads();
    if (n < N) {
        const float* yr = ylds[grp];
        float a = b1s[l];
#pragma unroll
        for (int k = 0; k < 32; k++) a += yr[k] * W1[k * 16 + l];
        a = a > 0.f ? a : 0.f;
        float contrib = a * w2s[l];
#pragma unroll
        for (int o = 1; o < 16; o <<= 1) contrib += __shfl_xor(contrib, o, 16);
        if (l == 0) out[n] = contrib + b2s;
    }
}

extern "C" void kernel_launch(void* const* d_in, const int* in_sizes, int n_in,
                              void* d_out, int out_size, void* d_ws, size_t ws_size,
                              hipStream_t stream) {
    const float* x    = (const float*)d_in[0];
    const int*   ei   = (const int*)d_in[1];
    const float* W_in = (const float*)d_in[2];
    const float* b_in = (const float*)d_in[3];
    const float* Wl1  = (const float*)d_in[4];
    const float* bl1  = (const float*)d_in[5];
    const float* Wr1  = (const float*)d_in[6];
    const float* g1   = (const float*)d_in[7];
    const float* be1  = (const float*)d_in[8];
    const float* Wl2  = (const float*)d_in[9];
    const float* bl2  = (const float*)d_in[10];
    const float* Wr2  = (const float*)d_in[11];
    const float* g2   = (const float*)d_in[12];
    const float* be2  = (const float*)d_in[13];
    const float* Wo1  = (const float*)d_in[14];
    const float* bo1  = (const float*)d_in[15];
    const float* Wo2  = (const float*)d_in[16];
    const float* bo2  = (const float*)d_in[17];
    float* out = (float*)d_out;

    const int N = NN, E = NE;
    const int* src = ei;
    const int* tgt = ei + E;

    // workspace layout
    char* w = (char*)d_ws;
    int* wh       = (int*)w;  w += (size_t)NW * 4;
    int* wrow     = (int*)w;  w += (size_t)(NW + 1) * 4;
    int* wcur     = (int*)w;  w += (size_t)NW * 4;
    int* rowstart = (int*)w;  w += (size_t)(NN + 1) * 4;
    w = (char*)(((uintptr_t)w + 15) & ~(uintptr_t)15);
    int* colw     = (int*)w;  w += (size_t)E * 4;
    int* colsort  = (int*)w;  w += (size_t)E * 4;
    f16* p1h  = (f16*)w;  w += (size_t)N * 64 * 2;
    f16* r1h  = (f16*)w;  w += (size_t)N * 64 * 2;
    f16* p2h  = (f16*)w;  w += (size_t)N * 32 * 2;
    f16* r2h  = (f16*)w;  w += (size_t)N * 32 * 2;
    f16* WinT = (f16*)w;  w += (size_t)128 * 104 * 2;
    f16* W2T  = (f16*)w;  w += (size_t)128 * 136 * 2;

    // ---- partition + CSR + dense pipeline (7 dispatches) ----
    hipMemsetAsync(wh, 0, (size_t)NW * 4, stream);
    k_prep_whist<<<PREPB + 256, 256, 0, stream>>>(W_in, Wl1, Wr1, WinT, W2T, tgt, wh, E / 4);
    k_wscan<<<1, 256, 0, stream>>>(wh, wrow, wcur, rowstart, NW);
    k_wfill_inproj<<<WFB + INPB, 256, 0, stream>>>(src, tgt, wcur, colw,
                                                   x, WinT, b_in, W2T, bl1, p1h, r1h, N);
    k_sort<<<NW, 256, 0, stream>>>(wrow, colw, rowstart, colsort, N);
    k_agg1_proj2<<<(N + 7) / 8, 256, 0, stream>>>((const __half2*)p1h, (const __half2*)r1h,
                                                  rowstart, colsort, g1, be1,
                                                  Wl2, Wr2, bl2, (__half*)p2h, (__half*)r2h, N);
    k_agg2_out<<<(N + 15) / 16, 256, 0, stream>>>((const __half2*)p2h, (const __half2*)r2h,
                                                  rowstart, colsort, g2, be2,
                                                  Wo1, bo1, Wo2, bo2, out, N);
}

// Round 9
// 106.763 us; speedup vs baseline: 5.7446x; 1.1114x over previous
//
#include <hip/hip_runtime.h>
#include <hip/hip_bf16.h>
#include <hip/hip_fp16.h>

#define NN 50000
#define NE 800000
#define EPS 1e-5f
#define NW 782            // ceil(NN/64) windows of 64 nodes
#define WFB 200           // wfill blocks
#define CHUNK (NE / WFB)  // 4000 edges per wfill block
#define CAP 2560          // LDS sort buffer
#define PREPB 64          // prep blocks in fused A
#define INPB ((NN + 31) / 32)   // in_proj1 blocks in fused B

typedef _Float16 f16;
typedef _Float16 f16x8 __attribute__((ext_vector_type(8)));
typedef float f32x4 __attribute__((ext_vector_type(4)));

__device__ __forceinline__ int waveInclScan(int v, int lane) {
#pragma unroll
    for (int o = 1; o < 64; o <<= 1) {
        int t = __shfl_up(v, o, 64);
        if (lane >= o) v += t;
    }
    return v;
}

// ---------------- fused A: weight prep (blocks <PREPB) | window hist (rest) ----------------
__global__ __launch_bounds__(256) void k_prep_whist(const float* __restrict__ Win,
                                                    const float* __restrict__ Wl,
                                                    const float* __restrict__ Wr,
                                                    const float* __restrict__ Wl2,
                                                    const float* __restrict__ Wr2,
                                                    const float* __restrict__ Wo1,
                                                    f16* __restrict__ WinT,
                                                    f16* __restrict__ W2T,
                                                    f16* __restrict__ W3T,
                                                    f16* __restrict__ Wo1T,
                                                    const int* __restrict__ tgt,
                                                    int* __restrict__ wh, int E4) {
    __shared__ int lh[NW];
    int tid = threadIdx.x;
    if (blockIdx.x < PREPB) {
        int i0 = blockIdx.x * 256 + tid;
        for (int i = i0; i < 128 * 104; i += PREPB * 256) {
            int c = i / 104, k = i - c * 104;
            float v = (k < 84) ? Win[k * 128 + c] : 0.f;
            WinT[c * 104 + k] = (f16)v;
        }
        for (int i = i0; i < 128 * 136; i += PREPB * 256) {
            int c = i / 136, k = i - c * 136;
            float v = 0.f;
            if (k < 128) v = (c < 64) ? Wl[k * 64 + c] : Wr[k * 64 + (c - 64)];
            W2T[c * 136 + k] = (f16)v;
        }
        for (int i = i0; i < 64 * 72; i += PREPB * 256) {
            int c = i / 72, k = i - c * 72;
            float v = 0.f;
            if (k < 64) v = (c < 32) ? Wl2[k * 32 + c] : Wr2[k * 32 + (c - 32)];
            W3T[c * 72 + k] = (f16)v;
        }
        for (int i = i0; i < 16 * 40; i += PREPB * 256) {
            int c = i / 40, k = i - c * 40;
            float v = (k < 32) ? Wo1[k * 16 + c] : 0.f;
            Wo1T[c * 40 + k] = (f16)v;
        }
    } else {
        int bid = blockIdx.x - PREPB;
        int nb = gridDim.x - PREPB;
        for (int i = tid; i < NW; i += 256) lh[i] = 0;
        __syncthreads();
        for (int i = bid * 256 + tid; i < E4; i += nb * 256) {
            int4 t = ((const int4*)tgt)[i];
            atomicAdd(&lh[t.x >> 6], 1);
            atomicAdd(&lh[t.y >> 6], 1);
            atomicAdd(&lh[t.z >> 6], 1);
            atomicAdd(&lh[t.w >> 6], 1);
        }
        __syncthreads();
        for (int i = tid; i < NW; i += 256) {
            int c = lh[i];
            if (c) atomicAdd(&wh[i], c);
        }
    }
}

// single-block carry scan over NW values -> wrow[0..NW], wcur copy; rowstart[NN] = E
__global__ __launch_bounds__(256) void k_wscan(const int* __restrict__ wh,
                                               int* __restrict__ wrow,
                                               int* __restrict__ wcur,
                                               int* __restrict__ rowstart, int n) {
    __shared__ int buf[256];
    __shared__ int carry_s;
    int tid = threadIdx.x;
    if (tid == 0) carry_s = 0;
    __syncthreads();
    for (int base = 0; base < n; base += 256) {
        int i = base + tid;
        int v = (i < n) ? wh[i] : 0;
        buf[tid] = v;
        __syncthreads();
        for (int off = 1; off < 256; off <<= 1) {
            int t = (tid >= off) ? buf[tid - off] : 0;
            __syncthreads();
            buf[tid] += t;
            __syncthreads();
        }
        int excl = buf[tid] - v;
        int c = carry_s;
        if (i < n) { wrow[i] = c + excl; wcur[i] = c + excl; }
        __syncthreads();
        if (tid == 0) carry_s = c + buf[255];
        __syncthreads();
    }
    if (tid == 0) { wrow[n] = carry_s; rowstart[NN] = carry_s; }
}

// ---------------- fused B: wfill (blocks <WFB) | MFMA in_proj1 (rest) ----------------
__global__ __launch_bounds__(256) void k_wfill_inproj(const int* __restrict__ src,
                                                      const int* __restrict__ tgt,
                                                      int* __restrict__ wcur,
                                                      int* __restrict__ colw,
                                                      const float* __restrict__ x,
                                                      const f16* __restrict__ WinT,
                                                      const float* __restrict__ bin,
                                                      const f16* __restrict__ W2T,
                                                      const float* __restrict__ bl,
                                                      f16* __restrict__ p1h,
                                                      f16* __restrict__ r1h, int N) {
    __shared__ int lh[NW];
    __shared__ int sb[NW];
    __shared__ __align__(16) f16 xs[32 * 104];
    __shared__ __align__(16) f16 hs[32 * 136];
    int tid = threadIdx.x;

    if (blockIdx.x < WFB) {
        int i4lo = (blockIdx.x * CHUNK) >> 2;
        int i4hi = i4lo + (CHUNK >> 2);
        for (int i = tid; i < NW; i += 256) lh[i] = 0;
        __syncthreads();
        for (int i4 = i4lo + tid; i4 < i4hi; i4 += 256) {
            int4 t = ((const int4*)tgt)[i4];
            atomicAdd(&lh[t.x >> 6], 1);
            atomicAdd(&lh[t.y >> 6], 1);
            atomicAdd(&lh[t.z >> 6], 1);
            atomicAdd(&lh[t.w >> 6], 1);
        }
        __syncthreads();
        for (int i = tid; i < NW; i += 256) {
            int c = lh[i];
            sb[i] = c ? atomicAdd(&wcur[i], c) : 0;
            lh[i] = 0;
        }
        __syncthreads();
        for (int i4 = i4lo + tid; i4 < i4hi; i4 += 256) {
            int4 t = ((const int4*)tgt)[i4];
            int4 s = ((const int4*)src)[i4];
            int w0 = t.x >> 6, r0 = atomicAdd(&lh[w0], 1);
            colw[sb[w0] + r0] = (s.x << 6) | (t.x & 63);
            int w1 = t.y >> 6, r1 = atomicAdd(&lh[w1], 1);
            colw[sb[w1] + r1] = (s.y << 6) | (t.y & 63);
            int w2 = t.z >> 6, r2 = atomicAdd(&lh[w2], 1);
            colw[sb[w2] + r2] = (s.z << 6) | (t.z & 63);
            int w3 = t.w >> 6, r3 = atomicAdd(&lh[w3], 1);
            colw[sb[w3] + r3] = (s.w << 6) | (t.w & 63);
        }
        return;
    }

    int node0 = (blockIdx.x - WFB) * 32;
    int lane = tid & 63;
    int wv = tid >> 6;
    int r = lane & 15;
    int q = lane >> 4;

    f16x8 b1[2][3];
#pragma unroll
    for (int nt = 0; nt < 2; nt++) {
        int c = (2 * wv + nt) * 16 + r;
#pragma unroll
        for (int ks = 0; ks < 3; ks++)
            b1[nt][ks] = *(const f16x8*)&WinT[c * 104 + ks * 32 + q * 8];
    }
    for (int i = tid; i < 32 * 96; i += 256) {
        int nd = i / 96, k = i - nd * 96;
        int g = node0 + nd;
        float v = (g < N && k < 84) ? x[(size_t)g * 84 + k] : 0.f;
        xs[nd * 104 + k] = (f16)v;
    }
    __syncthreads();

    f32x4 acc[2][2] = {};
#pragma unroll
    for (int ks = 0; ks < 3; ks++) {
        int k0 = ks * 32;
        f16x8 a[2];
#pragma unroll
        for (int mt = 0; mt < 2; mt++)
            a[mt] = *(const f16x8*)&xs[(mt * 16 + r) * 104 + k0 + q * 8];
#pragma unroll
        for (int mt = 0; mt < 2; mt++)
#pragma unroll
            for (int nt = 0; nt < 2; nt++)
                acc[mt][nt] = __builtin_amdgcn_mfma_f32_16x16x32_f16(a[mt], b1[nt][ks], acc[mt][nt], 0, 0, 0);
    }

    f16x8 b2[2][4];
#pragma unroll
    for (int nt = 0; nt < 2; nt++) {
        int c = (2 * wv + nt) * 16 + r;
#pragma unroll
        for (int ks = 0; ks < 4; ks++)
            b2[nt][ks] = *(const f16x8*)&W2T[c * 136 + ks * 32 + q * 8];
    }

#pragma unroll
    for (int nt = 0; nt < 2; nt++) {
        int c = (2 * wv + nt) * 16 + r;
        float bb = bin[c];
#pragma unroll
        for (int mt = 0; mt < 2; mt++)
#pragma unroll
            for (int v = 0; v < 4; v++) {
                int row = mt * 16 + q * 4 + v;
                float val = acc[mt][nt][v] + bb;
                hs[row * 136 + c] = (f16)(val > 0.f ? val : 0.f);
            }
    }
    __syncthreads();

    f32x4 acc2[2][2] = {};
#pragma unroll
    for (int ks = 0; ks < 4; ks++) {
        int k0 = ks * 32;
        f16x8 a[2];
#pragma unroll
        for (int mt = 0; mt < 2; mt++)
            a[mt] = *(const f16x8*)&hs[(mt * 16 + r) * 136 + k0 + q * 8];
#pragma unroll
        for (int mt = 0; mt < 2; mt++)
#pragma unroll
            for (int nt = 0; nt < 2; nt++)
                acc2[mt][nt] = __builtin_amdgcn_mfma_f32_16x16x32_f16(a[mt], b2[nt][ks], acc2[mt][nt], 0, 0, 0);
    }

#pragma unroll
    for (int nt = 0; nt < 2; nt++) {
        int c = (2 * wv + nt) * 16 + r;
        float bb = (c >= 64) ? bl[c - 64] : 0.f;
#pragma unroll
        for (int mt = 0; mt < 2; mt++)
#pragma unroll
            for (int v = 0; v < 4; v++) {
                int n = node0 + mt * 16 + q * 4 + v;
                if (n < N) {
                    float val = acc2[mt][nt][v];
                    if (c < 64) p1h[(size_t)n * 64 + c] = (f16)val;
                    else        r1h[(size_t)n * 64 + (c - 64)] = (f16)(val + bb);
                }
            }
    }
}

// per-window LDS counting sort -> node-level CSR (rowstart, colsorted)
__global__ __launch_bounds__(256) void k_sort(const int* __restrict__ wrow,
                                              const int* __restrict__ colw,
                                              int* __restrict__ rowstart,
                                              int* __restrict__ colsorted, int N) {
    __shared__ int cnt[64], cur[64];
    __shared__ int sorted[CAP];
    int wb = blockIdx.x, tid = threadIdx.x;
    int s0 = wrow[wb], s1 = wrow[wb + 1];
    int len = s1 - s0;
    if (tid < 64) cnt[tid] = 0;
    __syncthreads();
    for (int i = s0 + tid; i < s1; i += 256) atomicAdd(&cnt[colw[i] & 63], 1);
    __syncthreads();
    if (tid < 64) {
        int v = cnt[tid];
        int incl = waveInclScan(v, tid);
        cur[tid] = incl - v;
        int n = (wb << 6) + tid;
        if (n < N) rowstart[n] = s0 + incl - v;
    }
    __syncthreads();
    if (len <= CAP) {
        for (int i = s0 + tid; i < s1; i += 256) {
            int pk = colw[i];
            int pos = atomicAdd(&cur[pk & 63], 1);
            sorted[pos] = pk >> 6;
        }
        __syncthreads();
        for (int i = tid; i < len; i += 256) colsorted[s0 + i] = sorted[i];
    } else {
        for (int i = s0 + tid; i < s1; i += 256) {
            int pk = colw[i];
            int pos = atomicAdd(&cur[pk & 63], 1);
            colsorted[s0 + pos] = pk >> 6;
        }
    }
}

#define F2ADD(a, b) { (a).x += (b).x; (a).y += (b).y; }

// (p1 fp16, r1 fp16, CSR) -> p2, r2 : mean-agg + LN + relu (gather phase),
// then proj2 via MFMA. 512 threads, 32 nodes/block.
__global__ __launch_bounds__(512) void k_agg1_proj2(const __half2* __restrict__ p1v,
                                                    const __half2* __restrict__ r1v,
                                                    const int* __restrict__ rowstart,
                                                    const int* __restrict__ col,
                                                    const float* __restrict__ g1,
                                                    const float* __restrict__ be1,
                                                    const f16* __restrict__ W3T,
                                                    const float* __restrict__ bl2,
                                                    f16* __restrict__ p2h,
                                                    f16* __restrict__ r2h, int N) {
    __shared__ __align__(16) f16 ys[32][72];   // 4.6 KB, LN+relu output tile
    int tid = threadIdx.x;
    int nb = blockIdx.x * 32;
    unsigned cc = tid & 31;
    int grp = tid >> 5;          // 16 groups of 32 lanes
    int lane = tid & 63;
    int wv = tid >> 6;           // 8 waves
    int r = lane & 15;
    int q = lane >> 4;

    // B-fragments for proj2 (L2-hot): wave wv -> (mt = wv>>2, nt = wv&3)
    int ntile = wv & 3;
    int mtile = wv >> 2;
    f16x8 b3[2];
#pragma unroll
    for (int ks = 0; ks < 2; ks++)
        b3[ks] = *(const f16x8*)&W3T[(ntile * 16 + r) * 72 + ks * 32 + q * 8];

    // gather + LN + relu for 2 nodes per group
#pragma unroll
    for (int t = 0; t < 2; t++) {
        int tl = grp * 2 + t;
        int n = nb + tl;
        if (n < N) {
            int s0 = rowstart[n], s1 = rowstart[n + 1];
            float2 a0 = make_float2(0.f, 0.f), a1 = a0, a2 = a0, a3 = a0;
            float2 a4 = a0, a5 = a0, a6 = a0, a7 = a0;
            int i = s0;
            for (; i + 7 < s1; i += 8) {
                unsigned c0 = col[i],     c1 = col[i + 1], c2 = col[i + 2], c3 = col[i + 3];
                unsigned c4 = col[i + 4], c5 = col[i + 5], c6 = col[i + 6], c7 = col[i + 7];
                float2 v0 = __half22float2(p1v[c0 * 32u + cc]);
                float2 v1 = __half22float2(p1v[c1 * 32u + cc]);
                float2 v2 = __half22float2(p1v[c2 * 32u + cc]);
                float2 v3 = __half22float2(p1v[c3 * 32u + cc]);
                float2 v4 = __half22float2(p1v[c4 * 32u + cc]);
                float2 v5 = __half22float2(p1v[c5 * 32u + cc]);
                float2 v6 = __half22float2(p1v[c6 * 32u + cc]);
                float2 v7 = __half22float2(p1v[c7 * 32u + cc]);
                F2ADD(a0, v0) F2ADD(a1, v1) F2ADD(a2, v2) F2ADD(a3, v3)
                F2ADD(a4, v4) F2ADD(a5, v5) F2ADD(a6, v6) F2ADD(a7, v7)
            }
            for (; i < s1; i++) {
                float2 v0 = __half22float2(p1v[(unsigned)col[i] * 32u + cc]);
                F2ADD(a0, v0)
            }
            F2ADD(a0, a4) F2ADD(a1, a5) F2ADD(a2, a6) F2ADD(a3, a7)
            F2ADD(a0, a2) F2ADD(a1, a3) F2ADD(a0, a1)
            int cnt = s1 - s0;
            float inv = 1.f / (float)(cnt > 1 ? cnt : 1);
            float2 rr = __half22float2(r1v[(unsigned)n * 32u + cc]);
            float vx = a0.x * inv + rr.x;
            float vy = a0.y * inv + rr.y;
            float s = vx + vy;
#pragma unroll
            for (int o = 1; o < 32; o <<= 1) s += __shfl_xor(s, o, 32);
            float m = s * (1.f / 64.f);
            float dx = vx - m, dy = vy - m;
            float qv = dx * dx + dy * dy;
#pragma unroll
            for (int o = 1; o < 32; o <<= 1) qv += __shfl_xor(qv, o, 32);
            float rs = rsqrtf(qv * (1.f / 64.f) + EPS);
            float y0 = dx * rs * g1[2 * cc] + be1[2 * cc];
            float y1 = dy * rs * g1[2 * cc + 1] + be1[2 * cc + 1];
            ys[tl][2 * cc]     = (f16)(y0 > 0.f ? y0 : 0.f);
            ys[tl][2 * cc + 1] = (f16)(y1 > 0.f ? y1 : 0.f);
        } else {
            ys[tl][2 * cc] = (f16)0.f;
            ys[tl][2 * cc + 1] = (f16)0.f;
        }
    }
    __syncthreads();

    // proj2 via MFMA: [32 x 64] @ [64 x 64] ([Wl2 | Wr2])
    f32x4 acc = {};
#pragma unroll
    for (int ks = 0; ks < 2; ks++) {
        f16x8 a = *(const f16x8*)&ys[mtile * 16 + r][ks * 32 + q * 8];
        acc = __builtin_amdgcn_mfma_f32_16x16x32_f16(a, b3[ks], acc, 0, 0, 0);
    }
    int c2 = ntile * 16 + r;
    float bb = (c2 >= 32) ? bl2[c2 - 32] : 0.f;
#pragma unroll
    for (int v = 0; v < 4; v++) {
        int n = nb + mtile * 16 + q * 4 + v;
        if (n < N) {
            float val = acc[v];
            if (c2 < 32) p2h[(size_t)n * 32 + c2] = (f16)val;
            else         r2h[(size_t)n * 32 + (c2 - 32)] = (f16)(val + bb);
        }
    }
}

// (p2 fp16, r2 fp16, CSR) -> out : mean-agg + LN + relu, then MLP (MFMA + reduce).
// 256 threads, 32 nodes/block.
__global__ __launch_bounds__(256) void k_agg2_out(const __half2* __restrict__ p2v,
                                                  const __half2* __restrict__ r2v,
                                                  const int* __restrict__ rowstart,
                                                  const int* __restrict__ col,
                                                  const float* __restrict__ g2,
                                                  const float* __restrict__ be2,
                                                  const f16* __restrict__ Wo1T,
                                                  const float* __restrict__ bo1,
                                                  const float* __restrict__ Wo2,
                                                  const float* __restrict__ bo2,
                                                  float* __restrict__ out, int N) {
    __shared__ __align__(16) f16 ys[32][40];   // 2.5 KB
    int tid = threadIdx.x;
    int nb = blockIdx.x * 32;
    unsigned l = tid & 15;
    int grp = tid >> 4;          // 16 groups of 16 lanes
    int lane = tid & 63;
    int wv = tid >> 6;           // 4 waves; waves 0,1 do the MFMA
    int r = lane & 15;
    int q = lane >> 4;

    f16x8 bo = *(const f16x8*)&Wo1T[r * 40 + q * 8];
    float b1v = bo1[r];
    float w2v = Wo2[r];

#pragma unroll
    for (int t = 0; t < 2; t++) {
        int tl = grp * 2 + t;
        int n = nb + tl;
        if (n < N) {
            int s0 = rowstart[n], s1 = rowstart[n + 1];
            float2 a0 = make_float2(0.f, 0.f), a1 = a0, a2 = a0, a3 = a0;
            float2 a4 = a0, a5 = a0, a6 = a0, a7 = a0;
            int i = s0;
            for (; i + 7 < s1; i += 8) {
                unsigned c0 = col[i],     c1 = col[i + 1], c2 = col[i + 2], c3 = col[i + 3];
                unsigned c4 = col[i + 4], c5 = col[i + 5], c6 = col[i + 6], c7 = col[i + 7];
                float2 v0 = __half22float2(p2v[c0 * 16u + l]);
                float2 v1 = __half22float2(p2v[c1 * 16u + l]);
                float2 v2 = __half22float2(p2v[c2 * 16u + l]);
                float2 v3 = __half22float2(p2v[c3 * 16u + l]);
                float2 v4 = __half22float2(p2v[c4 * 16u + l]);
                float2 v5 = __half22float2(p2v[c5 * 16u + l]);
                float2 v6 = __half22float2(p2v[c6 * 16u + l]);
                float2 v7 = __half22float2(p2v[c7 * 16u + l]);
                F2ADD(a0, v0) F2ADD(a1, v1) F2ADD(a2, v2) F2ADD(a3, v3)
                F2ADD(a4, v4) F2ADD(a5, v5) F2ADD(a6, v6) F2ADD(a7, v7)
            }
            for (; i < s1; i++) {
                float2 v0 = __half22float2(p2v[(unsigned)col[i] * 16u + l]);
                F2ADD(a0, v0)
            }
            F2ADD(a0, a4) F2ADD(a1, a5) F2ADD(a2, a6) F2ADD(a3, a7)
            F2ADD(a0, a2) F2ADD(a1, a3) F2ADD(a0, a1)
            int cnt = s1 - s0;
            float inv = 1.f / (float)(cnt > 1 ? cnt : 1);
            float2 rr = __half22float2(r2v[(unsigned)n * 16u + l]);
            float vx = a0.x * inv + rr.x;
            float vy = a0.y * inv + rr.y;
            float s = vx + vy;
#pragma unroll
            for (int o = 1; o < 16; o <<= 1) s += __shfl_xor(s, o, 16);
            float m = s * (1.f / 32.f);
            float dx = vx - m, dy = vy - m;
            float qv = dx * dx + dy * dy;
#pragma unroll
            for (int o = 1; o < 16; o <<= 1) qv += __shfl_xor(qv, o, 16);
            float rs = rsqrtf(qv * (1.f / 32.f) + EPS);
            float y0 = dx * rs * g2[2 * l] + be2[2 * l];
            float y1 = dy * rs * g2[2 * l + 1] + be2[2 * l + 1];
            ys[tl][2 * l]     = (f16)(y0 > 0.f ? y0 : 0.f);
            ys[tl][2 * l + 1] = (f16)(y1 > 0.f ? y1 : 0.f);
        } else {
            ys[tl][2 * l] = (f16)0.f;
            ys[tl][2 * l + 1] = (f16)0.f;
        }
    }
    __syncthreads();

    // MLP: hidden = relu(y@Wo1+bo1) (MFMA), out = hidden@Wo2 + bo2 (shuffle reduce)
    if (wv < 2) {
        f16x8 a = *(const f16x8*)&ys[wv * 16 + r][q * 8];
        f32x4 acc = {};
        acc = __builtin_amdgcn_mfma_f32_16x16x32_f16(a, bo, acc, 0, 0, 0);
#pragma unroll
        for (int v = 0; v < 4; v++) {
            float h = acc[v] + b1v;
            h = h > 0.f ? h : 0.f;
            float contrib = h * w2v;
#pragma unroll
            for (int o = 1; o < 16; o <<= 1) contrib += __shfl_xor(contrib, o, 16);
            int n = nb + wv * 16 + q * 4 + v;
            if (r == 0 && n < N) out[n] = contrib + bo2[0];
        }
    }
}

extern "C" void kernel_launch(void* const* d_in, const int* in_sizes, int n_in,
                              void* d_out, int out_size, void* d_ws, size_t ws_size,
                              hipStream_t stream) {
    const float* x    = (const float*)d_in[0];
    const int*   ei   = (const int*)d_in[1];
    const float* W_in = (const float*)d_in[2];
    const float* b_in = (const float*)d_in[3];
    const float* Wl1  = (const float*)d_in[4];
    const float* bl1  = (const float*)d_in[5];
    const float* Wr1  = (const float*)d_in[6];
    const float* g1   = (const float*)d_in[7];
    const float* be1  = (const float*)d_in[8];
    const float* Wl2  = (const float*)d_in[9];
    const float* bl2  = (const float*)d_in[10];
    const float* Wr2  = (const float*)d_in[11];
    const float* g2   = (const float*)d_in[12];
    const float* be2  = (const float*)d_in[13];
    const float* Wo1  = (const float*)d_in[14];
    const float* bo1  = (const float*)d_in[15];
    const float* Wo2  = (const float*)d_in[16];
    const float* bo2  = (const float*)d_in[17];
    float* out = (float*)d_out;

    const int N = NN, E = NE;
    const int* src = ei;
    const int* tgt = ei + E;

    // workspace layout
    char* w = (char*)d_ws;
    int* wh       = (int*)w;  w += (size_t)NW * 4;
    int* wrow     = (int*)w;  w += (size_t)(NW + 1) * 4;
    int* wcur     = (int*)w;  w += (size_t)NW * 4;
    int* rowstart = (int*)w;  w += (size_t)(NN + 1) * 4;
    w = (char*)(((uintptr_t)w + 15) & ~(uintptr_t)15);
    int* colw     = (int*)w;  w += (size_t)E * 4;
    int* colsort  = (int*)w;  w += (size_t)E * 4;
    f16* p1h  = (f16*)w;  w += (size_t)N * 64 * 2;
    f16* r1h  = (f16*)w;  w += (size_t)N * 64 * 2;
    f16* p2h  = (f16*)w;  w += (size_t)N * 32 * 2;
    f16* r2h  = (f16*)w;  w += (size_t)N * 32 * 2;
    f16* WinT = (f16*)w;  w += (size_t)128 * 104 * 2;
    f16* W2T  = (f16*)w;  w += (size_t)128 * 136 * 2;
    f16* W3T  = (f16*)w;  w += (size_t)64 * 72 * 2;
    f16* Wo1T = (f16*)w;  w += (size_t)16 * 40 * 2;

    // ---- partition + CSR + dense pipeline (7 dispatches) ----
    hipMemsetAsync(wh, 0, (size_t)NW * 4, stream);
    k_prep_whist<<<PREPB + 256, 256, 0, stream>>>(W_in, Wl1, Wr1, Wl2, Wr2, Wo1,
                                                  WinT, W2T, W3T, Wo1T, tgt, wh, E / 4);
    k_wscan<<<1, 256, 0, stream>>>(wh, wrow, wcur, rowstart, NW);
    k_wfill_inproj<<<WFB + INPB, 256, 0, stream>>>(src, tgt, wcur, colw,
                                                   x, WinT, b_in, W2T, bl1, p1h, r1h, N);
    k_sort<<<NW, 256, 0, stream>>>(wrow, colw, rowstart, colsort, N);
    k_agg1_proj2<<<(N + 31) / 32, 512, 0, stream>>>((const __half2*)p1h, (const __half2*)r1h,
                                                    rowstart, colsort, g1, be1,
                                                    W3T, bl2, p2h, r2h, N);
    k_agg2_out<<<(N + 31) / 32, 256, 0, stream>>>((const __half2*)p2h, (const __half2*)r2h,
                                                  rowstart, colsort, g2, be2,
                                                  Wo1T, bo1, Wo2, bo2, out, N);
}

// Round 10
// 105.409 us; speedup vs baseline: 5.8184x; 1.0128x over previous
//
#include <hip/hip_runtime.h>
#include <hip/hip_bf16.h>
#include <hip/hip_fp16.h>

#define NN 50000
#define NE 800000
#define EPS 1e-5f
#define NW 782            // ceil(NN/64) windows of 64 nodes
#define WFB 200           // wfill blocks
#define CHUNK (NE / WFB)  // 4000 edges per wfill block
#define CAP 2560          // LDS sort buffer
#define PREPB 64          // prep blocks in fused A
#define INPB ((NN + 31) / 32)   // in_proj1 blocks in fused B

typedef _Float16 f16;
typedef _Float16 f16x8 __attribute__((ext_vector_type(8)));
typedef float f32x4 __attribute__((ext_vector_type(4)));

__global__ void k_zero(int* __restrict__ p, int n) {
    int i = blockIdx.x * blockDim.x + threadIdx.x;
    if (i < n) p[i] = 0;
}

__device__ __forceinline__ int waveInclScan(int v, int lane) {
#pragma unroll
    for (int o = 1; o < 64; o <<= 1) {
        int t = __shfl_up(v, o, 64);
        if (lane >= o) v += t;
    }
    return v;
}

// ---------------- fused A: weight prep (blocks <PREPB) | window hist (rest) ----------------
__global__ __launch_bounds__(256) void k_prep_whist(const float* __restrict__ Win,
                                                    const float* __restrict__ Wl,
                                                    const float* __restrict__ Wr,
                                                    const float* __restrict__ Wl2,
                                                    const float* __restrict__ Wr2,
                                                    const float* __restrict__ Wo1,
                                                    f16* __restrict__ WinT,
                                                    f16* __restrict__ W2T,
                                                    f16* __restrict__ W3T,
                                                    f16* __restrict__ Wo1T,
                                                    const int* __restrict__ tgt,
                                                    int* __restrict__ wh, int E4) {
    __shared__ int lh[NW];
    int tid = threadIdx.x;
    if (blockIdx.x < PREPB) {
        int i0 = blockIdx.x * 256 + tid;
        for (int i = i0; i < 128 * 104; i += PREPB * 256) {
            int c = i / 104, k = i - c * 104;
            float v = (k < 84) ? Win[k * 128 + c] : 0.f;
            WinT[c * 104 + k] = (f16)v;
        }
        for (int i = i0; i < 128 * 136; i += PREPB * 256) {
            int c = i / 136, k = i - c * 136;
            float v = 0.f;
            if (k < 128) v = (c < 64) ? Wl[k * 64 + c] : Wr[k * 64 + (c - 64)];
            W2T[c * 136 + k] = (f16)v;
        }
        for (int i = i0; i < 64 * 72; i += PREPB * 256) {
            int c = i / 72, k = i - c * 72;
            float v = 0.f;
            if (k < 64) v = (c < 32) ? Wl2[k * 32 + c] : Wr2[k * 32 + (c - 32)];
            W3T[c * 72 + k] = (f16)v;
        }
        for (int i = i0; i < 16 * 40; i += PREPB * 256) {
            int c = i / 40, k = i - c * 40;
            float v = (k < 32) ? Wo1[k * 16 + c] : 0.f;
            Wo1T[c * 40 + k] = (f16)v;
        }
    } else {
        int bid = blockIdx.x - PREPB;
        int nb = gridDim.x - PREPB;
        for (int i = tid; i < NW; i += 256) lh[i] = 0;
        __syncthreads();
        for (int i = bid * 256 + tid; i < E4; i += nb * 256) {
            int4 t = ((const int4*)tgt)[i];
            atomicAdd(&lh[t.x >> 6], 1);
            atomicAdd(&lh[t.y >> 6], 1);
            atomicAdd(&lh[t.z >> 6], 1);
            atomicAdd(&lh[t.w >> 6], 1);
        }
        __syncthreads();
        for (int i = tid; i < NW; i += 256) {
            int c = lh[i];
            if (c) atomicAdd(&wh[i], c);
        }
    }
}

// single-block carry scan over NW values -> wrow[0..NW], wcur copy; rowstart[NN] = E
__global__ __launch_bounds__(256) void k_wscan(const int* __restrict__ wh,
                                               int* __restrict__ wrow,
                                               int* __restrict__ wcur,
                                               int* __restrict__ rowstart, int n) {
    __shared__ int buf[256];
    __shared__ int carry_s;
    int tid = threadIdx.x;
    if (tid == 0) carry_s = 0;
    __syncthreads();
    for (int base = 0; base < n; base += 256) {
        int i = base + tid;
        int v = (i < n) ? wh[i] : 0;
        buf[tid] = v;
        __syncthreads();
        for (int off = 1; off < 256; off <<= 1) {
            int t = (tid >= off) ? buf[tid - off] : 0;
            __syncthreads();
            buf[tid] += t;
            __syncthreads();
        }
        int excl = buf[tid] - v;
        int c = carry_s;
        if (i < n) { wrow[i] = c + excl; wcur[i] = c + excl; }
        __syncthreads();
        if (tid == 0) carry_s = c + buf[255];
        __syncthreads();
    }
    if (tid == 0) { wrow[n] = carry_s; rowstart[NN] = carry_s; }
}

// ---------------- fused B: wfill (blocks <WFB) | MFMA in_proj1 (rest) ----------------
__global__ __launch_bounds__(256) void k_wfill_inproj(const int* __restrict__ src,
                                                      const int* __restrict__ tgt,
                                                      int* __restrict__ wcur,
                                                      int* __restrict__ colw,
                                                      const float* __restrict__ x,
                                                      const f16* __restrict__ WinT,
                                                      const float* __restrict__ bin,
                                                      const f16* __restrict__ W2T,
                                                      const float* __restrict__ bl,
                                                      f16* __restrict__ p1h,
                                                      f16* __restrict__ r1h, int N) {
    __shared__ int lh[NW];
    __shared__ int sb[NW];
    __shared__ __align__(16) f16 xs[32 * 104];
    __shared__ __align__(16) f16 hs[32 * 136];
    int tid = threadIdx.x;

    if (blockIdx.x < WFB) {
        int i4lo = (blockIdx.x * CHUNK) >> 2;
        int i4hi = i4lo + (CHUNK >> 2);
        for (int i = tid; i < NW; i += 256) lh[i] = 0;
        __syncthreads();
        for (int i4 = i4lo + tid; i4 < i4hi; i4 += 256) {
            int4 t = ((const int4*)tgt)[i4];
            atomicAdd(&lh[t.x >> 6], 1);
            atomicAdd(&lh[t.y >> 6], 1);
            atomicAdd(&lh[t.z >> 6], 1);
            atomicAdd(&lh[t.w >> 6], 1);
        }
        __syncthreads();
        for (int i = tid; i < NW; i += 256) {
            int c = lh[i];
            sb[i] = c ? atomicAdd(&wcur[i], c) : 0;
            lh[i] = 0;
        }
        __syncthreads();
        for (int i4 = i4lo + tid; i4 < i4hi; i4 += 256) {
            int4 t = ((const int4*)tgt)[i4];
            int4 s = ((const int4*)src)[i4];
            int w0 = t.x >> 6, r0 = atomicAdd(&lh[w0], 1);
            colw[sb[w0] + r0] = (s.x << 6) | (t.x & 63);
            int w1 = t.y >> 6, r1 = atomicAdd(&lh[w1], 1);
            colw[sb[w1] + r1] = (s.y << 6) | (t.y & 63);
            int w2 = t.z >> 6, r2 = atomicAdd(&lh[w2], 1);
            colw[sb[w2] + r2] = (s.z << 6) | (t.z & 63);
            int w3 = t.w >> 6, r3 = atomicAdd(&lh[w3], 1);
            colw[sb[w3] + r3] = (s.w << 6) | (t.w & 63);
        }
        return;
    }

    int node0 = (blockIdx.x - WFB) * 32;
    int lane = tid & 63;
    int wv = tid >> 6;
    int r = lane & 15;
    int q = lane >> 4;

    f16x8 b1[2][3];
#pragma unroll
    for (int nt = 0; nt < 2; nt++) {
        int c = (2 * wv + nt) * 16 + r;
#pragma unroll
        for (int ks = 0; ks < 3; ks++)
            b1[nt][ks] = *(const f16x8*)&WinT[c * 104 + ks * 32 + q * 8];
    }
    for (int i = tid; i < 32 * 96; i += 256) {
        int nd = i / 96, k = i - nd * 96;
        int g = node0 + nd;
        float v = (g < N && k < 84) ? x[(size_t)g * 84 + k] : 0.f;
        xs[nd * 104 + k] = (f16)v;
    }
    __syncthreads();

    f32x4 acc[2][2] = {};
#pragma unroll
    for (int ks = 0; ks < 3; ks++) {
        int k0 = ks * 32;
        f16x8 a[2];
#pragma unroll
        for (int mt = 0; mt < 2; mt++)
            a[mt] = *(const f16x8*)&xs[(mt * 16 + r) * 104 + k0 + q * 8];
#pragma unroll
        for (int mt = 0; mt < 2; mt++)
#pragma unroll
            for (int nt = 0; nt < 2; nt++)
                acc[mt][nt] = __builtin_amdgcn_mfma_f32_16x16x32_f16(a[mt], b1[nt][ks], acc[mt][nt], 0, 0, 0);
    }

    f16x8 b2[2][4];
#pragma unroll
    for (int nt = 0; nt < 2; nt++) {
        int c = (2 * wv + nt) * 16 + r;
#pragma unroll
        for (int ks = 0; ks < 4; ks++)
            b2[nt][ks] = *(const f16x8*)&W2T[c * 136 + ks * 32 + q * 8];
    }

#pragma unroll
    for (int nt = 0; nt < 2; nt++) {
        int c = (2 * wv + nt) * 16 + r;
        float bb = bin[c];
#pragma unroll
        for (int mt = 0; mt < 2; mt++)
#pragma unroll
            for (int v = 0; v < 4; v++) {
                int row = mt * 16 + q * 4 + v;
                float val = acc[mt][nt][v] + bb;
                hs[row * 136 + c] = (f16)(val > 0.f ? val : 0.f);
            }
    }
    __syncthreads();

    f32x4 acc2[2][2] = {};
#pragma unroll
    for (int ks = 0; ks < 4; ks++) {
        int k0 = ks * 32;
        f16x8 a[2];
#pragma unroll
        for (int mt = 0; mt < 2; mt++)
            a[mt] = *(const f16x8*)&hs[(mt * 16 + r) * 136 + k0 + q * 8];
#pragma unroll
        for (int mt = 0; mt < 2; mt++)
#pragma unroll
            for (int nt = 0; nt < 2; nt++)
                acc2[mt][nt] = __builtin_amdgcn_mfma_f32_16x16x32_f16(a[mt], b2[nt][ks], acc2[mt][nt], 0, 0, 0);
    }

#pragma unroll
    for (int nt = 0; nt < 2; nt++) {
        int c = (2 * wv + nt) * 16 + r;
        float bb = (c >= 64) ? bl[c - 64] : 0.f;
#pragma unroll
        for (int mt = 0; mt < 2; mt++)
#pragma unroll
            for (int v = 0; v < 4; v++) {
                int n = node0 + mt * 16 + q * 4 + v;
                if (n < N) {
                    float val = acc2[mt][nt][v];
                    if (c < 64) p1h[(size_t)n * 64 + c] = (f16)val;
                    else        r1h[(size_t)n * 64 + (c - 64)] = (f16)(val + bb);
                }
            }
    }
}

// per-window LDS counting sort -> node-level CSR (rowstart, colsorted)
__global__ __launch_bounds__(256) void k_sort(const int* __restrict__ wrow,
                                              const int* __restrict__ colw,
                                              int* __restrict__ rowstart,
                                              int* __restrict__ colsorted, int N) {
    __shared__ int cnt[64], cur[64];
    __shared__ int sorted[CAP];
    int wb = blockIdx.x, tid = threadIdx.x;
    int s0 = wrow[wb], s1 = wrow[wb + 1];
    int len = s1 - s0;
    if (tid < 64) cnt[tid] = 0;
    __syncthreads();
    for (int i = s0 + tid; i < s1; i += 256) atomicAdd(&cnt[colw[i] & 63], 1);
    __syncthreads();
    if (tid < 64) {
        int v = cnt[tid];
        int incl = waveInclScan(v, tid);
        cur[tid] = incl - v;
        int n = (wb << 6) + tid;
        if (n < N) rowstart[n] = s0 + incl - v;
    }
    __syncthreads();
    if (len <= CAP) {
        for (int i = s0 + tid; i < s1; i += 256) {
            int pk = colw[i];
            int pos = atomicAdd(&cur[pk & 63], 1);
            sorted[pos] = pk >> 6;
        }
        __syncthreads();
        for (int i = tid; i < len; i += 256) colsorted[s0 + i] = sorted[i];
    } else {
        for (int i = s0 + tid; i < s1; i += 256) {
            int pk = colw[i];
            int pos = atomicAdd(&cur[pk & 63], 1);
            colsorted[s0 + pos] = pk >> 6;
        }
    }
}

#define F2ADD(a, b) { (a).x += (b).x; (a).y += (b).y; }

// (p1 fp16, r1 fp16, CSR) -> p2, r2 : mean-agg + LN + relu (gather phase),
// then proj2 via MFMA. 512 threads, 32 nodes/block.
__global__ __launch_bounds__(512) void k_agg1_proj2(const __half2* __restrict__ p1v,
                                                    const __half2* __restrict__ r1v,
                                                    const int* __restrict__ rowstart,
                                                    const int* __restrict__ col,
                                                    const float* __restrict__ g1,
                                                    const float* __restrict__ be1,
                                                    const f16* __restrict__ W3T,
                                                    const float* __restrict__ bl2,
                                                    f16* __restrict__ p2h,
                                                    f16* __restrict__ r2h, int N) {
    __shared__ __align__(16) f16 ys[32][72];   // 4.6 KB, LN+relu output tile
    int tid = threadIdx.x;
    int nb = blockIdx.x * 32;
    unsigned cc = tid & 31;
    int grp = tid >> 5;          // 16 groups of 32 lanes
    int lane = tid & 63;
    int wv = tid >> 6;           // 8 waves
    int r = lane & 15;
    int q = lane >> 4;

    // B-fragments for proj2 (L2-hot): wave wv -> (mt = wv>>2, nt = wv&3)
    int ntile = wv & 3;
    int mtile = wv >> 2;
    f16x8 b3[2];
#pragma unroll
    for (int ks = 0; ks < 2; ks++)
        b3[ks] = *(const f16x8*)&W3T[(ntile * 16 + r) * 72 + ks * 32 + q * 8];

    // gather + LN + relu for 2 nodes per group
#pragma unroll
    for (int t = 0; t < 2; t++) {
        int tl = grp * 2 + t;
        int n = nb + tl;
        if (n < N) {
            int s0 = rowstart[n], s1 = rowstart[n + 1];
            float2 a0 = make_float2(0.f, 0.f), a1 = a0, a2 = a0, a3 = a0;
            float2 a4 = a0, a5 = a0, a6 = a0, a7 = a0;
            int i = s0;
            for (; i + 7 < s1; i += 8) {
                unsigned c0 = col[i],     c1 = col[i + 1], c2 = col[i + 2], c3 = col[i + 3];
                unsigned c4 = col[i + 4], c5 = col[i + 5], c6 = col[i + 6], c7 = col[i + 7];
                float2 v0 = __half22float2(p1v[c0 * 32u + cc]);
                float2 v1 = __half22float2(p1v[c1 * 32u + cc]);
                float2 v2 = __half22float2(p1v[c2 * 32u + cc]);
                float2 v3 = __half22float2(p1v[c3 * 32u + cc]);
                float2 v4 = __half22float2(p1v[c4 * 32u + cc]);
                float2 v5 = __half22float2(p1v[c5 * 32u + cc]);
                float2 v6 = __half22float2(p1v[c6 * 32u + cc]);
                float2 v7 = __half22float2(p1v[c7 * 32u + cc]);
                F2ADD(a0, v0) F2ADD(a1, v1) F2ADD(a2, v2) F2ADD(a3, v3)
                F2ADD(a4, v4) F2ADD(a5, v5) F2ADD(a6, v6) F2ADD(a7, v7)
            }
            for (; i < s1; i++) {
                float2 v0 = __half22float2(p1v[(unsigned)col[i] * 32u + cc]);
                F2ADD(a0, v0)
            }
            F2ADD(a0, a4) F2ADD(a1, a5) F2ADD(a2, a6) F2ADD(a3, a7)
            F2ADD(a0, a2) F2ADD(a1, a3) F2ADD(a0, a1)
            int cnt = s1 - s0;
            float inv = 1.f / (float)(cnt > 1 ? cnt : 1);
            float2 rr = __half22float2(r1v[(unsigned)n * 32u + cc]);
            float vx = a0.x * inv + rr.x;
            float vy = a0.y * inv + rr.y;
            float s = vx + vy;
#pragma unroll
            for (int o = 1; o < 32; o <<= 1) s += __shfl_xor(s, o, 32);
            float m = s * (1.f / 64.f);
            float dx = vx - m, dy = vy - m;
            float qv = dx * dx + dy * dy;
#pragma unroll
            for (int o = 1; o < 32; o <<= 1) qv += __shfl_xor(qv, o, 32);
            float rs = rsqrtf(qv * (1.f / 64.f) + EPS);
            float y0 = dx * rs * g1[2 * cc] + be1[2 * cc];
            float y1 = dy * rs * g1[2 * cc + 1] + be1[2 * cc + 1];
            ys[tl][2 * cc]     = (f16)(y0 > 0.f ? y0 : 0.f);
            ys[tl][2 * cc + 1] = (f16)(y1 > 0.f ? y1 : 0.f);
        } else {
            ys[tl][2 * cc] = (f16)0.f;
            ys[tl][2 * cc + 1] = (f16)0.f;
        }
    }
    __syncthreads();

    // proj2 via MFMA: [32 x 64] @ [64 x 64] ([Wl2 | Wr2])
    f32x4 acc = {};
#pragma unroll
    for (int ks = 0; ks < 2; ks++) {
        f16x8 a = *(const f16x8*)&ys[mtile * 16 + r][ks * 32 + q * 8];
        acc = __builtin_amdgcn_mfma_f32_16x16x32_f16(a, b3[ks], acc, 0, 0, 0);
    }
    int c2 = ntile * 16 + r;
    float bb = (c2 >= 32) ? bl2[c2 - 32] : 0.f;
#pragma unroll
    for (int v = 0; v < 4; v++) {
        int n = nb + mtile * 16 + q * 4 + v;
        if (n < N) {
            float val = acc[v];
            if (c2 < 32) p2h[(size_t)n * 32 + c2] = (f16)val;
            else         r2h[(size_t)n * 32 + (c2 - 32)] = (f16)(val + bb);
        }
    }
}

// (p2 fp16, r2 fp16, CSR) -> out : mean-agg + LN + relu, then MLP (MFMA + reduce).
// 256 threads, 32 nodes/block.
__global__ __launch_bounds__(256) void k_agg2_out(const __half2* __restrict__ p2v,
                                                  const __half2* __restrict__ r2v,
                                                  const int* __restrict__ rowstart,
                                                  const int* __restrict__ col,
                                                  const float* __restrict__ g2,
                                                  const float* __restrict__ be2,
                                                  const f16* __restrict__ Wo1T,
                                                  const float* __restrict__ bo1,
                                                  const float* __restrict__ Wo2,
                                                  const float* __restrict__ bo2,
                                                  float* __restrict__ out, int N) {
    __shared__ __align__(16) f16 ys[32][40];   // 2.5 KB
    int tid = threadIdx.x;
    int nb = blockIdx.x * 32;
    unsigned l = tid & 15;
    int grp = tid >> 4;          // 16 groups of 16 lanes
    int lane = tid & 63;
    int wv = tid >> 6;           // 4 waves; waves 0,1 do the MFMA
    int r = lane & 15;
    int q = lane >> 4;

    f16x8 bo = *(const f16x8*)&Wo1T[r * 40 + q * 8];
    float b1v = bo1[r];
    float w2v = Wo2[r];

#pragma unroll
    for (int t = 0; t < 2; t++) {
        int tl = grp * 2 + t;
        int n = nb + tl;
        if (n < N) {
            int s0 = rowstart[n], s1 = rowstart[n + 1];
            float2 a0 = make_float2(0.f, 0.f), a1 = a0, a2 = a0, a3 = a0;
            float2 a4 = a0, a5 = a0, a6 = a0, a7 = a0;
            int i = s0;
            for (; i + 7 < s1; i += 8) {
                unsigned c0 = col[i],     c1 = col[i + 1], c2 = col[i + 2], c3 = col[i + 3];
                unsigned c4 = col[i + 4], c5 = col[i + 5], c6 = col[i + 6], c7 = col[i + 7];
                float2 v0 = __half22float2(p2v[c0 * 16u + l]);
                float2 v1 = __half22float2(p2v[c1 * 16u + l]);
                float2 v2 = __half22float2(p2v[c2 * 16u + l]);
                float2 v3 = __half22float2(p2v[c3 * 16u + l]);
                float2 v4 = __half22float2(p2v[c4 * 16u + l]);
                float2 v5 = __half22float2(p2v[c5 * 16u + l]);
                float2 v6 = __half22float2(p2v[c6 * 16u + l]);
                float2 v7 = __half22float2(p2v[c7 * 16u + l]);
                F2ADD(a0, v0) F2ADD(a1, v1) F2ADD(a2, v2) F2ADD(a3, v3)
                F2ADD(a4, v4) F2ADD(a5, v5) F2ADD(a6, v6) F2ADD(a7, v7)
            }
            for (; i < s1; i++) {
                float2 v0 = __half22float2(p2v[(unsigned)col[i] * 16u + l]);
                F2ADD(a0, v0)
            }
            F2ADD(a0, a4) F2ADD(a1, a5) F2ADD(a2, a6) F2ADD(a3, a7)
            F2ADD(a0, a2) F2ADD(a1, a3) F2ADD(a0, a1)
            int cnt = s1 - s0;
            float inv = 1.f / (float)(cnt > 1 ? cnt : 1);
            float2 rr = __half22float2(r2v[(unsigned)n * 16u + l]);
            float vx = a0.x * inv + rr.x;
            float vy = a0.y * inv + rr.y;
            float s = vx + vy;
#pragma unroll
            for (int o = 1; o < 16; o <<= 1) s += __shfl_xor(s, o, 16);
            float m = s * (1.f / 32.f);
            float dx = vx - m, dy = vy - m;
            float qv = dx * dx + dy * dy;
#pragma unroll
            for (int o = 1; o < 16; o <<= 1) qv += __shfl_xor(qv, o, 16);
            float rs = rsqrtf(qv * (1.f / 32.f) + EPS);
            float y0 = dx * rs * g2[2 * l] + be2[2 * l];
            float y1 = dy * rs * g2[2 * l + 1] + be2[2 * l + 1];
            ys[tl][2 * l]     = (f16)(y0 > 0.f ? y0 : 0.f);
            ys[tl][2 * l + 1] = (f16)(y1 > 0.f ? y1 : 0.f);
        } else {
            ys[tl][2 * l] = (f16)0.f;
            ys[tl][2 * l + 1] = (f16)0.f;
        }
    }
    __syncthreads();

    // MLP: hidden = relu(y@Wo1+bo1) (MFMA), out = hidden@Wo2 + bo2 (shuffle reduce)
    if (wv < 2) {
        f16x8 a = *(const f16x8*)&ys[wv * 16 + r][q * 8];
        f32x4 acc = {};
        acc = __builtin_amdgcn_mfma_f32_16x16x32_f16(a, bo, acc, 0, 0, 0);
#pragma unroll
        for (int v = 0; v < 4; v++) {
            float h = acc[v] + b1v;
            h = h > 0.f ? h : 0.f;
            float contrib = h * w2v;
#pragma unroll
            for (int o = 1; o < 16; o <<= 1) contrib += __shfl_xor(contrib, o, 16);
            int n = nb + wv * 16 + q * 4 + v;
            if (r == 0 && n < N) out[n] = contrib + bo2[0];
        }
    }
}

extern "C" void kernel_launch(void* const* d_in, const int* in_sizes, int n_in,
                              void* d_out, int out_size, void* d_ws, size_t ws_size,
                              hipStream_t stream) {
    const float* x    = (const float*)d_in[0];
    const int*   ei   = (const int*)d_in[1];
    const float* W_in = (const float*)d_in[2];
    const float* b_in = (const float*)d_in[3];
    const float* Wl1  = (const float*)d_in[4];
    const float* bl1  = (const float*)d_in[5];
    const float* Wr1  = (const float*)d_in[6];
    const float* g1   = (const float*)d_in[7];
    const float* be1  = (const float*)d_in[8];
    const float* Wl2  = (const float*)d_in[9];
    const float* bl2  = (const float*)d_in[10];
    const float* Wr2  = (const float*)d_in[11];
    const float* g2   = (const float*)d_in[12];
    const float* be2  = (const float*)d_in[13];
    const float* Wo1  = (const float*)d_in[14];
    const float* bo1  = (const float*)d_in[15];
    const float* Wo2  = (const float*)d_in[16];
    const float* bo2  = (const float*)d_in[17];
    float* out = (float*)d_out;

    const int N = NN, E = NE;
    const int* src = ei;
    const int* tgt = ei + E;

    // workspace layout
    char* w = (char*)d_ws;
    int* wh       = (int*)w;  w += (size_t)NW * 4;
    int* wrow     = (int*)w;  w += (size_t)(NW + 1) * 4;
    int* wcur     = (int*)w;  w += (size_t)NW * 4;
    int* rowstart = (int*)w;  w += (size_t)(NN + 1) * 4;
    w = (char*)(((uintptr_t)w + 15) & ~(uintptr_t)15);
    int* colw     = (int*)w;  w += (size_t)E * 4;
    int* colsort  = (int*)w;  w += (size_t)E * 4;
    f16* p1h  = (f16*)w;  w += (size_t)N * 64 * 2;
    f16* r1h  = (f16*)w;  w += (size_t)N * 64 * 2;
    f16* p2h  = (f16*)w;  w += (size_t)N * 32 * 2;
    f16* r2h  = (f16*)w;  w += (size_t)N * 32 * 2;
    f16* WinT = (f16*)w;  w += (size_t)128 * 104 * 2;
    f16* W2T  = (f16*)w;  w += (size_t)128 * 136 * 2;
    f16* W3T  = (f16*)w;  w += (size_t)64 * 72 * 2;
    f16* Wo1T = (f16*)w;  w += (size_t)16 * 40 * 2;

    // ---- partition + CSR + dense pipeline (7 dispatches, no runtime fill) ----
    k_zero<<<4, 256, 0, stream>>>(wh, NW);
    k_prep_whist<<<PREPB + 256, 256, 0, stream>>>(W_in, Wl1, Wr1, Wl2, Wr2, Wo1,
                                                  WinT, W2T, W3T, Wo1T, tgt, wh, E / 4);
    k_wscan<<<1, 256, 0, stream>>>(wh, wrow, wcur, rowstart, NW);
    k_wfill_inproj<<<WFB + INPB, 256, 0, stream>>>(src, tgt, wcur, colw,
                                                   x, WinT, b_in, W2T, bl1, p1h, r1h, N);
    k_sort<<<NW, 256, 0, stream>>>(wrow, colw, rowstart, colsort, N);
    k_agg1_proj2<<<(N + 31) / 32, 512, 0, stream>>>((const __half2*)p1h, (const __half2*)r1h,
                                                    rowstart, colsort, g1, be1,
                                                    W3T, bl2, p2h, r2h, N);
    k_agg2_out<<<(N + 31) / 32, 256, 0, stream>>>((const __half2*)p2h, (const __half2*)r2h,
                                                  rowstart, colsort, g2, be2,
                                                  Wo1T, bo1, Wo2, bo2, out, N);
}

// Round 11
// 85.150 us; speedup vs baseline: 7.2028x; 1.2379x over previous
//
#include <hip/hip_runtime.h>
#include <hip/hip_bf16.h>
#include <hip/hip_fp16.h>

#define NN 50000
#define NE 800000
#define EPS 1e-5f
#define NW 782            // ceil(NN/64) windows of 64 nodes
#define CAP 2560          // fixed per-window colw slots (max window load ~1150)
#define WFB 200           // wfill blocks
#define CHUNK (NE / WFB)  // 4000 edges per wfill block
#define PREPB 64          // prep blocks
#define INPB ((NN + 31) / 32)

typedef _Float16 f16;
typedef _Float16 f16x8 __attribute__((ext_vector_type(8)));
typedef float f32x4 __attribute__((ext_vector_type(4)));

__device__ __forceinline__ int waveInclScan(int v, int lane) {
#pragma unroll
    for (int o = 1; o < 64; o <<= 1) {
        int t = __shfl_up(v, o, 64);
        if (lane >= o) v += t;
    }
    return v;
}

// ---------------- prep: weight transposes + wcur init (one tiny dispatch) ----------------
__global__ __launch_bounds__(256) void k_prep_init(const float* __restrict__ Win,
                                                   const float* __restrict__ Wl,
                                                   const float* __restrict__ Wr,
                                                   const float* __restrict__ Wl2,
                                                   const float* __restrict__ Wr2,
                                                   const float* __restrict__ Wo1,
                                                   f16* __restrict__ WinT,
                                                   f16* __restrict__ W2T,
                                                   f16* __restrict__ W3T,
                                                   f16* __restrict__ Wo1T,
                                                   int* __restrict__ wcur) {
    int i0 = blockIdx.x * 256 + threadIdx.x;
    for (int i = i0; i < 128 * 104; i += PREPB * 256) {
        int c = i / 104, k = i - c * 104;
        float v = (k < 84) ? Win[k * 128 + c] : 0.f;
        WinT[c * 104 + k] = (f16)v;
    }
    for (int i = i0; i < 128 * 136; i += PREPB * 256) {
        int c = i / 136, k = i - c * 136;
        float v = 0.f;
        if (k < 128) v = (c < 64) ? Wl[k * 64 + c] : Wr[k * 64 + (c - 64)];
        W2T[c * 136 + k] = (f16)v;
    }
    for (int i = i0; i < 64 * 72; i += PREPB * 256) {
        int c = i / 72, k = i - c * 72;
        float v = 0.f;
        if (k < 64) v = (c < 32) ? Wl2[k * 32 + c] : Wr2[k * 32 + (c - 32)];
        W3T[c * 72 + k] = (f16)v;
    }
    for (int i = i0; i < 16 * 40; i += PREPB * 256) {
        int c = i / 40, k = i - c * 40;
        float v = (k < 32) ? Wo1[k * 16 + c] : 0.f;
        Wo1T[c * 40 + k] = (f16)v;
    }
    for (int i = i0; i < NW; i += PREPB * 256) wcur[i] = i * CAP;
}

// ---------------- fused: wfill (blocks <WFB) | MFMA in_proj1 (rest) ----------------
__global__ __launch_bounds__(256) void k_wfill_inproj(const int* __restrict__ src,
                                                      const int* __restrict__ tgt,
                                                      int* __restrict__ wcur,
                                                      int* __restrict__ colw,
                                                      const float* __restrict__ x,
                                                      const f16* __restrict__ WinT,
                                                      const float* __restrict__ bin,
                                                      const f16* __restrict__ W2T,
                                                      const float* __restrict__ bl,
                                                      f16* __restrict__ p1h,
                                                      f16* __restrict__ r1h, int N) {
    __shared__ int lh[NW];
    __shared__ int sb[NW];
    __shared__ __align__(16) f16 xs[32 * 104];
    __shared__ __align__(16) f16 hs[32 * 136];
    int tid = threadIdx.x;

    if (blockIdx.x < WFB) {
        // span-reserved window partition into CAP-strided colw
        int i4lo = (blockIdx.x * CHUNK) >> 2;
        int i4hi = i4lo + (CHUNK >> 2);
        for (int i = tid; i < NW; i += 256) lh[i] = 0;
        __syncthreads();
        for (int i4 = i4lo + tid; i4 < i4hi; i4 += 256) {
            int4 t = ((const int4*)tgt)[i4];
            atomicAdd(&lh[t.x >> 6], 1);
            atomicAdd(&lh[t.y >> 6], 1);
            atomicAdd(&lh[t.z >> 6], 1);
            atomicAdd(&lh[t.w >> 6], 1);
        }
        __syncthreads();
        for (int i = tid; i < NW; i += 256) {
            int c = lh[i];
            sb[i] = c ? atomicAdd(&wcur[i], c) : 0;
            lh[i] = 0;
        }
        __syncthreads();
        for (int i4 = i4lo + tid; i4 < i4hi; i4 += 256) {
            int4 t = ((const int4*)tgt)[i4];
            int4 s = ((const int4*)src)[i4];
            int w0 = t.x >> 6, r0 = atomicAdd(&lh[w0], 1);
            colw[sb[w0] + r0] = (s.x << 6) | (t.x & 63);
            int w1 = t.y >> 6, r1 = atomicAdd(&lh[w1], 1);
            colw[sb[w1] + r1] = (s.y << 6) | (t.y & 63);
            int w2 = t.z >> 6, r2 = atomicAdd(&lh[w2], 1);
            colw[sb[w2] + r2] = (s.z << 6) | (t.z & 63);
            int w3 = t.w >> 6, r3 = atomicAdd(&lh[w3], 1);
            colw[sb[w3] + r3] = (s.w << 6) | (t.w & 63);
        }
        return;
    }

    // ---- in_proj1: x -> h1 (LDS) -> p1, r1 via MFMA ----
    int node0 = (blockIdx.x - WFB) * 32;
    int lane = tid & 63;
    int wv = tid >> 6;
    int r = lane & 15;
    int q = lane >> 4;

    f16x8 b1[2][3];
#pragma unroll
    for (int nt = 0; nt < 2; nt++) {
        int c = (2 * wv + nt) * 16 + r;
#pragma unroll
        for (int ks = 0; ks < 3; ks++)
            b1[nt][ks] = *(const f16x8*)&WinT[c * 104 + ks * 32 + q * 8];
    }
    // float4-vectorized x staging: 672 float4 per block (x rows are 16B-aligned: 84*4=336)
    for (int i = tid; i < 672; i += 256) {
        int nd = i / 21, k4 = i - nd * 21;
        int g = node0 + nd;
        float4 v = make_float4(0.f, 0.f, 0.f, 0.f);
        if (g < N) v = ((const float4*)x)[(size_t)g * 21 + k4];
        f16* dst = &xs[nd * 104 + k4 * 4];
        dst[0] = (f16)v.x; dst[1] = (f16)v.y; dst[2] = (f16)v.z; dst[3] = (f16)v.w;
    }
    for (int i = tid; i < 32 * 12; i += 256) {
        int nd = i / 12, k = 84 + (i - nd * 12);
        xs[nd * 104 + k] = (f16)0.f;
    }
    __syncthreads();

    f32x4 acc[2][2] = {};
#pragma unroll
    for (int ks = 0; ks < 3; ks++) {
        int k0 = ks * 32;
        f16x8 a[2];
#pragma unroll
        for (int mt = 0; mt < 2; mt++)
            a[mt] = *(const f16x8*)&xs[(mt * 16 + r) * 104 + k0 + q * 8];
#pragma unroll
        for (int mt = 0; mt < 2; mt++)
#pragma unroll
            for (int nt = 0; nt < 2; nt++)
                acc[mt][nt] = __builtin_amdgcn_mfma_f32_16x16x32_f16(a[mt], b1[nt][ks], acc[mt][nt], 0, 0, 0);
    }

    f16x8 b2[2][4];
#pragma unroll
    for (int nt = 0; nt < 2; nt++) {
        int c = (2 * wv + nt) * 16 + r;
#pragma unroll
        for (int ks = 0; ks < 4; ks++)
            b2[nt][ks] = *(const f16x8*)&W2T[c * 136 + ks * 32 + q * 8];
    }

#pragma unroll
    for (int nt = 0; nt < 2; nt++) {
        int c = (2 * wv + nt) * 16 + r;
        float bb = bin[c];
#pragma unroll
        for (int mt = 0; mt < 2; mt++)
#pragma unroll
            for (int v = 0; v < 4; v++) {
                int row = mt * 16 + q * 4 + v;
                float val = acc[mt][nt][v] + bb;
                hs[row * 136 + c] = (f16)(val > 0.f ? val : 0.f);
            }
    }
    __syncthreads();

    f32x4 acc2[2][2] = {};
#pragma unroll
    for (int ks = 0; ks < 4; ks++) {
        int k0 = ks * 32;
        f16x8 a[2];
#pragma unroll
        for (int mt = 0; mt < 2; mt++)
            a[mt] = *(const f16x8*)&hs[(mt * 16 + r) * 136 + k0 + q * 8];
#pragma unroll
        for (int mt = 0; mt < 2; mt++)
#pragma unroll
            for (int nt = 0; nt < 2; nt++)
                acc2[mt][nt] = __builtin_amdgcn_mfma_f32_16x16x32_f16(a[mt], b2[nt][ks], acc2[mt][nt], 0, 0, 0);
    }

#pragma unroll
    for (int nt = 0; nt < 2; nt++) {
        int c = (2 * wv + nt) * 16 + r;
        float bb = (c >= 64) ? bl[c - 64] : 0.f;
#pragma unroll
        for (int mt = 0; mt < 2; mt++)
#pragma unroll
            for (int v = 0; v < 4; v++) {
                int n = node0 + mt * 16 + q * 4 + v;
                if (n < N) {
                    float val = acc2[mt][nt][v];
                    if (c < 64) p1h[(size_t)n * 64 + c] = (f16)val;
                    else        r1h[(size_t)n * 64 + (c - 64)] = (f16)(val + bb);
                }
            }
    }
}

#define F2ADD(a, b) { (a).x += (b).x; (a).y += (b).y; }

// ---------------- agg1 (per-window): LDS sort -> gather+LN -> MFMA proj2 ----------------
__global__ __launch_bounds__(512) void k_agg1_proj2(const __half2* __restrict__ p1v,
                                                    const __half2* __restrict__ r1v,
                                                    const int* __restrict__ wcur,
                                                    const int* __restrict__ colw,
                                                    const float* __restrict__ g1,
                                                    const float* __restrict__ be1,
                                                    const f16* __restrict__ W3T,
                                                    const float* __restrict__ bl2,
                                                    f16* __restrict__ p2h,
                                                    f16* __restrict__ r2h, int N) {
    __shared__ int cnt[64], start[64], cur[64];
    __shared__ int sorted[CAP];
    __shared__ __align__(16) f16 ys[64][72];
    int tid = threadIdx.x;
    int wb = blockIdx.x;
    int base = wb * CAP;
    int nb = wb << 6;
    int len = wcur[wb] - base;
    if (len > CAP) len = CAP;

    unsigned cc = tid & 31;
    int grp = tid >> 5;       // 16 groups of 32 lanes
    int lane = tid & 63;
    int wv = tid >> 6;        // 8 waves
    int r = lane & 15;
    int q = lane >> 4;

    // proj2 B-fragments hoisted (overlaps with sort/gather latency)
    int mt = wv & 3;
    int ntbase = (wv >> 2) * 2;
    f16x8 b3[2][2];
#pragma unroll
    for (int j = 0; j < 2; j++)
#pragma unroll
        for (int ks = 0; ks < 2; ks++)
            b3[j][ks] = *(const f16x8*)&W3T[((ntbase + j) * 16 + r) * 72 + ks * 32 + q * 8];

    // ---- per-window counting sort in LDS ----
    if (tid < 64) cnt[tid] = 0;
    __syncthreads();
    for (int i = tid; i < len; i += 512) atomicAdd(&cnt[colw[base + i] & 63], 1);
    __syncthreads();
    if (tid < 64) {
        int v = cnt[tid];
        int incl = waveInclScan(v, tid);
        start[tid] = incl - v;
        cur[tid] = incl - v;
    }
    __syncthreads();
    for (int i = tid; i < len; i += 512) {
        int pk = colw[base + i];
        int pos = atomicAdd(&cur[pk & 63], 1);
        sorted[pos] = pk >> 6;
    }
    __syncthreads();

    // ---- gather + LN + relu: 4 nodes per 32-lane group ----
#pragma unroll
    for (int t = 0; t < 4; t++) {
        int tl = grp + 16 * t;
        int n = nb + tl;
        if (n < N) {
            int s0 = start[tl], s1 = start[tl] + cnt[tl];
            float2 a0 = make_float2(0.f, 0.f), a1 = a0, a2 = a0, a3 = a0;
            float2 a4 = a0, a5 = a0, a6 = a0, a7 = a0;
            int i = s0;
            for (; i + 7 < s1; i += 8) {
                unsigned c0 = sorted[i],     c1 = sorted[i + 1], c2 = sorted[i + 2], c3 = sorted[i + 3];
                unsigned c4 = sorted[i + 4], c5 = sorted[i + 5], c6 = sorted[i + 6], c7 = sorted[i + 7];
                float2 v0 = __half22float2(p1v[c0 * 32u + cc]);
                float2 v1 = __half22float2(p1v[c1 * 32u + cc]);
                float2 v2 = __half22float2(p1v[c2 * 32u + cc]);
                float2 v3 = __half22float2(p1v[c3 * 32u + cc]);
                float2 v4 = __half22float2(p1v[c4 * 32u + cc]);
                float2 v5 = __half22float2(p1v[c5 * 32u + cc]);
                float2 v6 = __half22float2(p1v[c6 * 32u + cc]);
                float2 v7 = __half22float2(p1v[c7 * 32u + cc]);
                F2ADD(a0, v0) F2ADD(a1, v1) F2ADD(a2, v2) F2ADD(a3, v3)
                F2ADD(a4, v4) F2ADD(a5, v5) F2ADD(a6, v6) F2ADD(a7, v7)
            }
            for (; i < s1; i++) {
                float2 v0 = __half22float2(p1v[(unsigned)sorted[i] * 32u + cc]);
                F2ADD(a0, v0)
            }
            F2ADD(a0, a4) F2ADD(a1, a5) F2ADD(a2, a6) F2ADD(a3, a7)
            F2ADD(a0, a2) F2ADD(a1, a3) F2ADD(a0, a1)
            int cntv = s1 - s0;
            float inv = 1.f / (float)(cntv > 1 ? cntv : 1);
            float2 rr = __half22float2(r1v[(unsigned)n * 32u + cc]);
            float vx = a0.x * inv + rr.x;
            float vy = a0.y * inv + rr.y;
            float s = vx + vy;
#pragma unroll
            for (int o = 1; o < 32; o <<= 1) s += __shfl_xor(s, o, 32);
            float m = s * (1.f / 64.f);
            float dx = vx - m, dy = vy - m;
            float qv = dx * dx + dy * dy;
#pragma unroll
            for (int o = 1; o < 32; o <<= 1) qv += __shfl_xor(qv, o, 32);
            float rs = rsqrtf(qv * (1.f / 64.f) + EPS);
            float y0 = dx * rs * g1[2 * cc] + be1[2 * cc];
            float y1 = dy * rs * g1[2 * cc + 1] + be1[2 * cc + 1];
            ys[tl][2 * cc]     = (f16)(y0 > 0.f ? y0 : 0.f);
            ys[tl][2 * cc + 1] = (f16)(y1 > 0.f ? y1 : 0.f);
        } else {
            ys[tl][2 * cc] = (f16)0.f;
            ys[tl][2 * cc + 1] = (f16)0.f;
        }
    }
    __syncthreads();

    // ---- proj2 via MFMA: [64 x 64] @ [64 x 64], 16 tile-jobs, 2 per wave ----
#pragma unroll
    for (int j = 0; j < 2; j++) {
        int nt = ntbase + j;
        f32x4 acc = {};
#pragma unroll
        for (int ks = 0; ks < 2; ks++) {
            f16x8 a = *(const f16x8*)&ys[mt * 16 + r][ks * 32 + q * 8];
            acc = __builtin_amdgcn_mfma_f32_16x16x32_f16(a, b3[j][ks], acc, 0, 0, 0);
        }
        int c2 = nt * 16 + r;
        float bb = (c2 >= 32) ? bl2[c2 - 32] : 0.f;
#pragma unroll
        for (int v = 0; v < 4; v++) {
            int n = nb + mt * 16 + q * 4 + v;
            if (n < N) {
                float val = acc[v];
                if (c2 < 32) p2h[(size_t)n * 32 + c2] = (f16)val;
                else         r2h[(size_t)n * 32 + (c2 - 32)] = (f16)(val + bb);
            }
        }
    }
}

// ---------------- agg2 (per-window): LDS sort -> gather+LN -> MFMA MLP ----------------
__global__ __launch_bounds__(512) void k_agg2_out(const __half2* __restrict__ p2v,
                                                  const __half2* __restrict__ r2v,
                                                  const int* __restrict__ wcur,
                                                  const int* __restrict__ colw,
                                                  const float* __restrict__ g2,
                                                  const float* __restrict__ be2,
                                                  const f16* __restrict__ Wo1T,
                                                  const float* __restrict__ bo1,
                                                  const float* __restrict__ Wo2,
                                                  const float* __restrict__ bo2,
                                                  float* __restrict__ out, int N) {
    __shared__ int cnt[64], start[64], cur[64];
    __shared__ int sorted[CAP];
    __shared__ __align__(16) f16 ys[64][40];
    int tid = threadIdx.x;
    int wb = blockIdx.x;
    int base = wb * CAP;
    int nb = wb << 6;
    int len = wcur[wb] - base;
    if (len > CAP) len = CAP;

    unsigned l = tid & 15;
    int grp = tid >> 4;       // 32 groups of 16 lanes
    int lane = tid & 63;
    int wv = tid >> 6;        // 8 waves; waves 0..3 do the MFMA
    int r = lane & 15;
    int q = lane >> 4;

    f16x8 bo = *(const f16x8*)&Wo1T[r * 40 + q * 8];
    float b1v = bo1[r];
    float w2v = Wo2[r];

    if (tid < 64) cnt[tid] = 0;
    __syncthreads();
    for (int i = tid; i < len; i += 512) atomicAdd(&cnt[colw[base + i] & 63], 1);
    __syncthreads();
    if (tid < 64) {
        int v = cnt[tid];
        int incl = waveInclScan(v, tid);
        start[tid] = incl - v;
        cur[tid] = incl - v;
    }
    __syncthreads();
    for (int i = tid; i < len; i += 512) {
        int pk = colw[base + i];
        int pos = atomicAdd(&cur[pk & 63], 1);
        sorted[pos] = pk >> 6;
    }
    __syncthreads();

    // gather + LN + relu: 2 nodes per 16-lane group
#pragma unroll
    for (int t = 0; t < 2; t++) {
        int tl = grp + 32 * t;
        int n = nb + tl;
        if (n < N) {
            int s0 = start[tl], s1 = start[tl] + cnt[tl];
            float2 a0 = make_float2(0.f, 0.f), a1 = a0, a2 = a0, a3 = a0;
            float2 a4 = a0, a5 = a0, a6 = a0, a7 = a0;
            int i = s0;
            for (; i + 7 < s1; i += 8) {
                unsigned c0 = sorted[i],     c1 = sorted[i + 1], c2 = sorted[i + 2], c3 = sorted[i + 3];
                unsigned c4 = sorted[i + 4], c5 = sorted[i + 5], c6 = sorted[i + 6], c7 = sorted[i + 7];
                float2 v0 = __half22float2(p2v[c0 * 16u + l]);
                float2 v1 = __half22float2(p2v[c1 * 16u + l]);
                float2 v2 = __half22float2(p2v[c2 * 16u + l]);
                float2 v3 = __half22float2(p2v[c3 * 16u + l]);
                float2 v4 = __half22float2(p2v[c4 * 16u + l]);
                float2 v5 = __half22float2(p2v[c5 * 16u + l]);
                float2 v6 = __half22float2(p2v[c6 * 16u + l]);
                float2 v7 = __half22float2(p2v[c7 * 16u + l]);
                F2ADD(a0, v0) F2ADD(a1, v1) F2ADD(a2, v2) F2ADD(a3, v3)
                F2ADD(a4, v4) F2ADD(a5, v5) F2ADD(a6, v6) F2ADD(a7, v7)
            }
            for (; i < s1; i++) {
                float2 v0 = __half22float2(p2v[(unsigned)sorted[i] * 16u + l]);
                F2ADD(a0, v0)
            }
            F2ADD(a0, a4) F2ADD(a1, a5) F2ADD(a2, a6) F2ADD(a3, a7)
            F2ADD(a0, a2) F2ADD(a1, a3) F2ADD(a0, a1)
            int cntv = s1 - s0;
            float inv = 1.f / (float)(cntv > 1 ? cntv : 1);
            float2 rr = __half22float2(r2v[(unsigned)n * 16u + l]);
            float vx = a0.x * inv + rr.x;
            float vy = a0.y * inv + rr.y;
            float s = vx + vy;
#pragma unroll
            for (int o = 1; o < 16; o <<= 1) s += __shfl_xor(s, o, 16);
            float m = s * (1.f / 32.f);
            float dx = vx - m, dy = vy - m;
            float qv = dx * dx + dy * dy;
#pragma unroll
            for (int o = 1; o < 16; o <<= 1) qv += __shfl_xor(qv, o, 16);
            float rs = rsqrtf(qv * (1.f / 32.f) + EPS);
            float y0 = dx * rs * g2[2 * l] + be2[2 * l];
            float y1 = dy * rs * g2[2 * l + 1] + be2[2 * l + 1];
            ys[tl][2 * l]     = (f16)(y0 > 0.f ? y0 : 0.f);
            ys[tl][2 * l + 1] = (f16)(y1 > 0.f ? y1 : 0.f);
        } else {
            ys[tl][2 * l] = (f16)0.f;
            ys[tl][2 * l + 1] = (f16)0.f;
        }
    }
    __syncthreads();

    // MLP: hidden = relu(y@Wo1+bo1) via MFMA ([64x32]@[32x16], 4 m-tiles on waves 0..3),
    // out = hidden@Wo2 + bo2 via 16-lane shuffle reduce.
    if (wv < 4) {
        f16x8 a = *(const f16x8*)&ys[wv * 16 + r][q * 8];
        f32x4 acc = {};
        acc = __builtin_amdgcn_mfma_f32_16x16x32_f16(a, bo, acc, 0, 0, 0);
#pragma unroll
        for (int v = 0; v < 4; v++) {
            float h = acc[v] + b1v;
            h = h > 0.f ? h : 0.f;
            float contrib = h * w2v;
#pragma unroll
            for (int o = 1; o < 16; o <<= 1) contrib += __shfl_xor(contrib, o, 16);
            int n = nb + wv * 16 + q * 4 + v;
            if (r == 0 && n < N) out[n] = contrib + bo2[0];
        }
    }
}

extern "C" void kernel_launch(void* const* d_in, const int* in_sizes, int n_in,
                              void* d_out, int out_size, void* d_ws, size_t ws_size,
                              hipStream_t stream) {
    const float* x    = (const float*)d_in[0];
    const int*   ei   = (const int*)d_in[1];
    const float* W_in = (const float*)d_in[2];
    const float* b_in = (const float*)d_in[3];
    const float* Wl1  = (const float*)d_in[4];
    const float* bl1  = (const float*)d_in[5];
    const float* Wr1  = (const float*)d_in[6];
    const float* g1   = (const float*)d_in[7];
    const float* be1  = (const float*)d_in[8];
    const float* Wl2  = (const float*)d_in[9];
    const float* bl2  = (const float*)d_in[10];
    const float* Wr2  = (const float*)d_in[11];
    const float* g2   = (const float*)d_in[12];
    const float* be2  = (const float*)d_in[13];
    const float* Wo1  = (const float*)d_in[14];
    const float* bo1  = (const float*)d_in[15];
    const float* Wo2  = (const float*)d_in[16];
    const float* bo2  = (const float*)d_in[17];
    float* out = (float*)d_out;

    const int N = NN, E = NE;
    const int* src = ei;
    const int* tgt = ei + E;

    // workspace layout
    char* w = (char*)d_ws;
    int* wcur = (int*)w;  w += (size_t)NW * 4;
    w = (char*)(((uintptr_t)w + 15) & ~(uintptr_t)15);
    int* colw = (int*)w;  w += (size_t)NW * CAP * 4;     // 8.0 MB, CAP-strided
    f16* p1h  = (f16*)w;  w += (size_t)N * 64 * 2;
    f16* r1h  = (f16*)w;  w += (size_t)N * 64 * 2;
    f16* p2h  = (f16*)w;  w += (size_t)N * 32 * 2;
    f16* r2h  = (f16*)w;  w += (size_t)N * 32 * 2;
    f16* WinT = (f16*)w;  w += (size_t)128 * 104 * 2;
    f16* W2T  = (f16*)w;  w += (size_t)128 * 136 * 2;
    f16* W3T  = (f16*)w;  w += (size_t)64 * 72 * 2;
    f16* Wo1T = (f16*)w;  w += (size_t)16 * 40 * 2;

    // ---- 4-dispatch pipeline ----
    k_prep_init<<<PREPB, 256, 0, stream>>>(W_in, Wl1, Wr1, Wl2, Wr2, Wo1,
                                           WinT, W2T, W3T, Wo1T, wcur);
    k_wfill_inproj<<<WFB + INPB, 256, 0, stream>>>(src, tgt, wcur, colw,
                                                   x, WinT, b_in, W2T, bl1, p1h, r1h, N);
    k_agg1_proj2<<<NW, 512, 0, stream>>>((const __half2*)p1h, (const __half2*)r1h,
                                         wcur, colw, g1, be1, W3T, bl2, p2h, r2h, N);
    k_agg2_out<<<NW, 512, 0, stream>>>((const __half2*)p2h, (const __half2*)r2h,
                                       wcur, colw, g2, be2, Wo1T, bo1, Wo2, bo2, out, N);
}